// Round 1
// baseline (666.673 us; speedup 1.0000x reference)
//
#include <hip/hip_runtime.h>
#include <math.h>

#define B_ 4
#define S_ 2048
#define D_ 768
#define H_ 12
#define DH_ 64
#define FF_ 3072

using short8  = __attribute__((ext_vector_type(8))) short;
using f32x4   = __attribute__((ext_vector_type(4))) float;
using float4v = __attribute__((ext_vector_type(4))) float;
using ushort4v= __attribute__((ext_vector_type(4))) unsigned short;

__device__ __forceinline__ unsigned short f2bf(float f) {
  unsigned u = __builtin_bit_cast(unsigned, f);
  u += 0x7FFFu + ((u >> 16) & 1u);   // round-to-nearest-even
  return (unsigned short)(u >> 16);
}

// ---------------- weight transpose + cast: in [K][N] f32 -> out [N][K] bf16 ----------------
__global__ __launch_bounds__(256) void transpose_cast_kernel(
    const float* __restrict__ in, unsigned short* __restrict__ out, int K, int N) {
  __shared__ float tile[32][33];
  int k0 = blockIdx.x * 32, n0 = blockIdx.y * 32;
  int tx = threadIdx.x, ty = threadIdx.y;
#pragma unroll
  for (int i = 0; i < 4; i++)
    tile[ty + 8*i][tx] = in[(size_t)(k0 + ty + 8*i) * N + n0 + tx];
  __syncthreads();
#pragma unroll
  for (int i = 0; i < 4; i++)
    out[(size_t)(n0 + ty + 8*i) * K + k0 + tx] = f2bf(tile[tx][ty + 8*i]);
}

// ---------------- LayerNorm: fp32 in -> bf16 out, one wave per row of 768 ----------------
__global__ __launch_bounds__(256) void layernorm_kernel(
    const float* __restrict__ x, const float* __restrict__ g,
    const float* __restrict__ b, unsigned short* __restrict__ out) {
  int wave = threadIdx.x >> 6, lane = threadIdx.x & 63;
  int row = blockIdx.x * 4 + wave;
  const float* xr = x + (size_t)row * D_;
  float4v v[3];
  float sum = 0.f, sq = 0.f;
#pragma unroll
  for (int i = 0; i < 3; i++) {
    v[i] = reinterpret_cast<const float4v*>(xr)[lane + 64*i];
#pragma unroll
    for (int j = 0; j < 4; j++) { sum += v[i][j]; sq += v[i][j]*v[i][j]; }
  }
#pragma unroll
  for (int d = 1; d < 64; d <<= 1) { sum += __shfl_xor(sum, d); sq += __shfl_xor(sq, d); }
  float mu   = sum * (1.0f / D_);
  float var  = sq  * (1.0f / D_) - mu * mu;
  float rstd = rsqrtf(var + 1e-5f);
  unsigned short* orow = out + (size_t)row * D_;
#pragma unroll
  for (int i = 0; i < 3; i++) {
    int idx = (lane + 64*i) * 4;
    ushort4v o;
#pragma unroll
    for (int j = 0; j < 4; j++)
      o[j] = f2bf((v[i][j] - mu) * rstd * g[idx + j] + b[idx + j]);
    *reinterpret_cast<ushort4v*>(orow + idx) = o;
  }
}

// ---------------- bf16 MFMA GEMM, 128x128 tile, BK=64, 4 waves ----------------
#define EPI_QKV   0
#define EPI_OPROJ 1
#define EPI_GELU  2
#define EPI_FINAL 3

template<int EPI>
__global__ __launch_bounds__(256) void gemm_kernel(
    const unsigned short* __restrict__ A, int lda,
    const unsigned short* __restrict__ BT, int K,
    const float* __restrict__ bias,
    const float* __restrict__ resid,
    float* __restrict__ outf,
    unsigned short* __restrict__ outh,
    int ldo) {
  __shared__ __attribute__((aligned(16))) unsigned short As[128*72];
  __shared__ __attribute__((aligned(16))) unsigned short Bs[128*72];
  int tid = threadIdx.x;
  int wave = tid >> 6, lane = tid & 63;
  int lrow = lane & 15, lk8 = (lane >> 4) * 8;
  int m0 = blockIdx.y * 128, n0 = blockIdx.x * 128;
  int wm = (wave >> 1) * 64, wn = (wave & 1) * 64;
  f32x4 acc[4][4] = {};
  for (int k0 = 0; k0 < K; k0 += 64) {
    __syncthreads();
#pragma unroll
    for (int i = 0; i < 4; i++) {
      int c = tid + 256*i; int r = c >> 3, kc = (c & 7) * 8;
      *reinterpret_cast<uint4*>(&As[r*72 + kc]) =
        *reinterpret_cast<const uint4*>(A + (size_t)(m0 + r) * lda + k0 + kc);
    }
#pragma unroll
    for (int i = 0; i < 4; i++) {
      int c = tid + 256*i; int r = c >> 3, kc = (c & 7) * 8;
      *reinterpret_cast<uint4*>(&Bs[r*72 + kc]) =
        *reinterpret_cast<const uint4*>(BT + (size_t)(n0 + r) * K + k0 + kc);
    }
    __syncthreads();
#pragma unroll
    for (int ks = 0; ks < 2; ks++) {
      short8 af[4], bf[4];
#pragma unroll
      for (int mi = 0; mi < 4; mi++)
        af[mi] = *reinterpret_cast<const short8*>(&As[(wm + mi*16 + lrow)*72 + ks*32 + lk8]);
#pragma unroll
      for (int ni = 0; ni < 4; ni++)
        bf[ni] = *reinterpret_cast<const short8*>(&Bs[(wn + ni*16 + lrow)*72 + ks*32 + lk8]);
#pragma unroll
      for (int mi = 0; mi < 4; mi++)
#pragma unroll
        for (int ni = 0; ni < 4; ni++)
          acc[mi][ni] = __builtin_amdgcn_mfma_f32_16x16x32_bf16(af[mi], bf[ni], acc[mi][ni], 0, 0, 0);
    }
  }
#pragma unroll
  for (int mi = 0; mi < 4; mi++) {
#pragma unroll
    for (int ni = 0; ni < 4; ni++) {
#pragma unroll
      for (int r = 0; r < 4; r++) {
        int gm = m0 + wm + mi*16 + (lane >> 4)*4 + r;
        int gn = n0 + wn + ni*16 + lrow;
        float v = acc[mi][ni][r] + bias[gn];
        if constexpr (EPI == EPI_QKV) {
          size_t idx = ((size_t)((gm >> 11) * H_ + (gn >> 6)) * S_ + (gm & 2047)) * DH_ + (gn & 63);
          outh[idx] = f2bf(v);
        } else if constexpr (EPI == EPI_OPROJ) {
          size_t idx = (size_t)gm * ldo + gn;
          outf[idx] = v + resid[idx];
        } else if constexpr (EPI == EPI_GELU) {
          float gv = 0.5f * v * (1.0f + erff(v * 0.70710678118654752f));
          outh[(size_t)gm * ldo + gn] = f2bf(gv);
        } else {  // EPI_FINAL
          size_t idx = (size_t)gm * ldo + gn;
          outf[idx] = v + resid[idx];
        }
      }
    }
  }
}

// ---------------- causal flash attention, 64 q-rows/block, 4 waves, 32-key tiles ----------------
__global__ __launch_bounds__(256) void attn_kernel(
    const unsigned short* __restrict__ q,
    const unsigned short* __restrict__ k,
    const unsigned short* __restrict__ v,
    unsigned short* __restrict__ o) {
  __shared__ __attribute__((aligned(16))) unsigned short VT[64*48];  // [dh][key] padded
  __shared__ __attribute__((aligned(16))) unsigned short P[4*16*48]; // per-wave [16 q][32 key] padded
  int tid = threadIdx.x;
  int wave = tid >> 6, lane = tid & 63;
  int lrow = lane & 15, lk8 = (lane >> 4) * 8, rbase = (lane >> 4) * 4;
  int bh = blockIdx.y, q0 = blockIdx.x * 64;
  int qw = q0 + wave * 16;
  const unsigned short* qb = q + (size_t)bh * S_ * DH_;
  const unsigned short* kb = k + (size_t)bh * S_ * DH_;
  const unsigned short* vb = v + (size_t)bh * S_ * DH_;
  short8 qf[2];
#pragma unroll
  for (int ks = 0; ks < 2; ks++)
    qf[ks] = *reinterpret_cast<const short8*>(qb + (size_t)(qw + lrow) * DH_ + ks*32 + lk8);
  f32x4 oacc[4] = {};
  float mst[4], lst[4];
#pragma unroll
  for (int r = 0; r < 4; r++) { mst[r] = -1e30f; lst[r] = 0.f; }
  int nt = q0 / 32 + 2;
  for (int kt = 0; kt < nt; kt++) {
    int kb0 = kt * 32;
    __syncthreads();
    { // stage V tile transposed: VT[dh][key]
      int key = tid >> 3, dh0 = (tid & 7) * 8;
      union { uint4 u; unsigned short s[8]; } cv;
      cv.u = *reinterpret_cast<const uint4*>(vb + (size_t)(kb0 + key) * DH_ + dh0);
#pragma unroll
      for (int j = 0; j < 8; j++)
        VT[(dh0 + j) * 48 + key] = cv.s[j];
    }
    __syncthreads();
    // scores S[16 q][32 key]
    f32x4 sc[2] = {};
#pragma unroll
    for (int sub = 0; sub < 2; sub++) {
#pragma unroll
      for (int ks = 0; ks < 2; ks++) {
        short8 kf = *reinterpret_cast<const short8*>(
            kb + (size_t)(kb0 + sub*16 + lrow) * DH_ + ks*32 + lk8);
        sc[sub] = __builtin_amdgcn_mfma_f32_16x16x32_bf16(qf[ks], kf, sc[sub], 0, 0, 0);
      }
    }
    // online softmax per q-row
#pragma unroll
    for (int r = 0; r < 4; r++) {
      int qr = qw + rbase + r;
      float s0 = sc[0][r] * 0.125f;
      float s1 = sc[1][r] * 0.125f;
      if (kb0 + lrow > qr)      s0 = -1e30f;
      if (kb0 + 16 + lrow > qr) s1 = -1e30f;
      float mx = fmaxf(s0, s1);
#pragma unroll
      for (int d = 1; d < 16; d <<= 1) mx = fmaxf(mx, __shfl_xor(mx, d));
      float mnew = fmaxf(mst[r], mx);
      float p0 = expf(s0 - mnew), p1 = expf(s1 - mnew);
      float fac = expf(mst[r] - mnew);
      float rs = p0 + p1;
#pragma unroll
      for (int d = 1; d < 16; d <<= 1) rs += __shfl_xor(rs, d);
      lst[r] = lst[r] * fac + rs;
      mst[r] = mnew;
#pragma unroll
      for (int nf = 0; nf < 4; nf++) oacc[nf][r] *= fac;
      P[(wave*16 + rbase + r) * 48 + lrow]      = f2bf(p0);
      P[(wave*16 + rbase + r) * 48 + 16 + lrow] = f2bf(p1);
    }
    // PV: A = P[16][32], B = V[32][64] via VT
    short8 pa = *reinterpret_cast<const short8*>(&P[(wave*16 + lrow) * 48 + lk8]);
#pragma unroll
    for (int nf = 0; nf < 4; nf++) {
      short8 vf = *reinterpret_cast<const short8*>(&VT[(nf*16 + lrow) * 48 + lk8]);
      oacc[nf] = __builtin_amdgcn_mfma_f32_16x16x32_bf16(pa, vf, oacc[nf], 0, 0, 0);
    }
  }
  int bb = bh / H_, hh = bh % H_;
#pragma unroll
  for (int nf = 0; nf < 4; nf++) {
#pragma unroll
    for (int r = 0; r < 4; r++) {
      float val = oacc[nf][r] / lst[r];
      int qr = qw + rbase + r;
      int dh = nf*16 + lrow;
      o[((size_t)(bb * S_ + qr)) * D_ + hh * DH_ + dh] = f2bf(val);
    }
  }
}

extern "C" void kernel_launch(void* const* d_in, const int* in_sizes, int n_in,
                              void* d_out, int out_size, void* d_ws, size_t ws_size,
                              hipStream_t stream) {
  (void)in_sizes; (void)n_in; (void)out_size; (void)ws_size;
  const float* x    = (const float*)d_in[0];
  const float* ln1g = (const float*)d_in[1];
  const float* ln1b = (const float*)d_in[2];
  const float* Wq   = (const float*)d_in[3];
  const float* bq   = (const float*)d_in[4];
  const float* Wk   = (const float*)d_in[5];
  const float* bk   = (const float*)d_in[6];
  const float* Wv   = (const float*)d_in[7];
  const float* bv   = (const float*)d_in[8];
  const float* Wo   = (const float*)d_in[9];
  const float* bo   = (const float*)d_in[10];
  const float* ln2g = (const float*)d_in[11];
  const float* ln2b = (const float*)d_in[12];
  const float* W1   = (const float*)d_in[13];
  const float* b1   = (const float*)d_in[14];
  const float* W2   = (const float*)d_in[15];
  const float* b2   = (const float*)d_in[16];
  float* out = (float*)d_out;

  char* ws = (char*)d_ws;
  size_t off = 0;
  auto alloc = [&](size_t bytes) {
    char* p = ws + off;
    off += (bytes + 255) & ~(size_t)255;
    return p;
  };
  unsigned short* WqT = (unsigned short*)alloc((size_t)D_*D_*2);
  unsigned short* WkT = (unsigned short*)alloc((size_t)D_*D_*2);
  unsigned short* WvT = (unsigned short*)alloc((size_t)D_*D_*2);
  unsigned short* WoT = (unsigned short*)alloc((size_t)D_*D_*2);
  unsigned short* W1T = (unsigned short*)alloc((size_t)D_*FF_*2);
  unsigned short* W2T = (unsigned short*)alloc((size_t)FF_*D_*2);
  unsigned short* h   = (unsigned short*)alloc((size_t)B_*S_*D_*2);
  unsigned short* qb  = (unsigned short*)alloc((size_t)B_*S_*D_*2);
  unsigned short* kbf = (unsigned short*)alloc((size_t)B_*S_*D_*2);
  unsigned short* vbf = (unsigned short*)alloc((size_t)B_*S_*D_*2);
  unsigned short* ob  = (unsigned short*)alloc((size_t)B_*S_*D_*2);
  unsigned short* ffb = qb;  // reuse q/k/v/o region (exactly 4*B*S*D*2 = B*S*FF*2 bytes)
  unsigned short* h2  = h;   // reuse h

  dim3 tb(32, 8);
  transpose_cast_kernel<<<dim3(D_/32,  D_/32),  tb, 0, stream>>>(Wq, WqT, D_,  D_);
  transpose_cast_kernel<<<dim3(D_/32,  D_/32),  tb, 0, stream>>>(Wk, WkT, D_,  D_);
  transpose_cast_kernel<<<dim3(D_/32,  D_/32),  tb, 0, stream>>>(Wv, WvT, D_,  D_);
  transpose_cast_kernel<<<dim3(D_/32,  D_/32),  tb, 0, stream>>>(Wo, WoT, D_,  D_);
  transpose_cast_kernel<<<dim3(D_/32,  FF_/32), tb, 0, stream>>>(W1, W1T, D_,  FF_);
  transpose_cast_kernel<<<dim3(FF_/32, D_/32),  tb, 0, stream>>>(W2, W2T, FF_, D_);

  layernorm_kernel<<<(B_*S_)/4, 256, 0, stream>>>(x, ln1g, ln1b, h);

  gemm_kernel<EPI_QKV><<<dim3(D_/128, (B_*S_)/128), 256, 0, stream>>>(
      h, D_, WqT, D_, bq, nullptr, nullptr, qb, D_);
  gemm_kernel<EPI_QKV><<<dim3(D_/128, (B_*S_)/128), 256, 0, stream>>>(
      h, D_, WkT, D_, bk, nullptr, nullptr, kbf, D_);
  gemm_kernel<EPI_QKV><<<dim3(D_/128, (B_*S_)/128), 256, 0, stream>>>(
      h, D_, WvT, D_, bv, nullptr, nullptr, vbf, D_);

  attn_kernel<<<dim3(S_/64, B_*H_), 256, 0, stream>>>(qb, kbf, vbf, ob);

  gemm_kernel<EPI_OPROJ><<<dim3(D_/128, (B_*S_)/128), 256, 0, stream>>>(
      ob, D_, WoT, D_, bo, x, out, nullptr, D_);

  layernorm_kernel<<<(B_*S_)/4, 256, 0, stream>>>(out, ln2g, ln2b, h2);

  gemm_kernel<EPI_GELU><<<dim3(FF_/128, (B_*S_)/128), 256, 0, stream>>>(
      h2, D_, W1T, D_, b1, nullptr, nullptr, ffb, FF_);

  gemm_kernel<EPI_FINAL><<<dim3(D_/128, (B_*S_)/128), 256, 0, stream>>>(
      ffb, FF_, W2T, FF_, b2, out, out, nullptr, D_);
}

// Round 2
// 541.131 us; speedup vs baseline: 1.2320x; 1.2320x over previous
//
#include <hip/hip_runtime.h>
#include <math.h>

#define B_ 4
#define S_ 2048
#define D_ 768
#define H_ 12
#define DH_ 64
#define FF_ 3072

using short8  = __attribute__((ext_vector_type(8))) short;
using f32x4   = __attribute__((ext_vector_type(4))) float;
using float4v = __attribute__((ext_vector_type(4))) float;
using ushort4v= __attribute__((ext_vector_type(4))) unsigned short;

__device__ __forceinline__ unsigned short f2bf(float f) {
  unsigned u = __builtin_bit_cast(unsigned, f);
  u += 0x7FFFu + ((u >> 16) & 1u);   // round-to-nearest-even
  return (unsigned short)(u >> 16);
}

// ---------------- weight transpose + cast: in [K][N] f32 -> out [N][K] bf16 ----------------
__global__ __launch_bounds__(256) void transpose_cast_kernel(
    const float* __restrict__ in, unsigned short* __restrict__ out, int K, int N) {
  __shared__ float tile[32][33];
  int k0 = blockIdx.x * 32, n0 = blockIdx.y * 32;
  int tx = threadIdx.x, ty = threadIdx.y;
#pragma unroll
  for (int i = 0; i < 4; i++)
    tile[ty + 8*i][tx] = in[(size_t)(k0 + ty + 8*i) * N + n0 + tx];
  __syncthreads();
#pragma unroll
  for (int i = 0; i < 4; i++)
    out[(size_t)(n0 + ty + 8*i) * K + k0 + tx] = f2bf(tile[tx][ty + 8*i]);
}

// ---------------- LayerNorm: fp32 in -> bf16 out, one wave per row of 768 ----------------
__global__ __launch_bounds__(256) void layernorm_kernel(
    const float* __restrict__ x, const float* __restrict__ g,
    const float* __restrict__ b, unsigned short* __restrict__ out) {
  int wave = threadIdx.x >> 6, lane = threadIdx.x & 63;
  int row = blockIdx.x * 4 + wave;
  const float* xr = x + (size_t)row * D_;
  float4v v[3];
  float sum = 0.f, sq = 0.f;
#pragma unroll
  for (int i = 0; i < 3; i++) {
    v[i] = reinterpret_cast<const float4v*>(xr)[lane + 64*i];
#pragma unroll
    for (int j = 0; j < 4; j++) { sum += v[i][j]; sq += v[i][j]*v[i][j]; }
  }
#pragma unroll
  for (int d = 1; d < 64; d <<= 1) { sum += __shfl_xor(sum, d); sq += __shfl_xor(sq, d); }
  float mu   = sum * (1.0f / D_);
  float var  = sq  * (1.0f / D_) - mu * mu;
  float rstd = rsqrtf(var + 1e-5f);
  unsigned short* orow = out + (size_t)row * D_;
#pragma unroll
  for (int i = 0; i < 3; i++) {
    int idx = (lane + 64*i) * 4;
    ushort4v o;
#pragma unroll
    for (int j = 0; j < 4; j++)
      o[j] = f2bf((v[i][j] - mu) * rstd * g[idx + j] + b[idx + j]);
    *reinterpret_cast<ushort4v*>(orow + idx) = o;
  }
}

// ---------------- bf16 MFMA GEMM, 128x128 tile, BK=64, 4 waves ----------------
#define EPI_QKV   0
#define EPI_OPROJ 1
#define EPI_GELU  2
#define EPI_FINAL 3

template<int EPI>
__global__ __launch_bounds__(256) void gemm_kernel(
    const unsigned short* __restrict__ A, int lda,
    const unsigned short* __restrict__ BT, int K,
    const float* __restrict__ bias,
    const float* __restrict__ resid,
    float* __restrict__ outf,
    unsigned short* __restrict__ outh,
    int ldo, float ascale) {
  __shared__ __attribute__((aligned(16))) unsigned short As[128*72];
  __shared__ __attribute__((aligned(16))) unsigned short Bs[128*72];
  int tid = threadIdx.x;
  int wave = tid >> 6, lane = tid & 63;
  int lrow = lane & 15, lk8 = (lane >> 4) * 8;
  int m0 = blockIdx.y * 128, n0 = blockIdx.x * 128;
  int wm = (wave >> 1) * 64, wn = (wave & 1) * 64;
  f32x4 acc[4][4] = {};
  for (int k0 = 0; k0 < K; k0 += 64) {
    __syncthreads();
#pragma unroll
    for (int i = 0; i < 4; i++) {
      int c = tid + 256*i; int r = c >> 3, kc = (c & 7) * 8;
      *reinterpret_cast<uint4*>(&As[r*72 + kc]) =
        *reinterpret_cast<const uint4*>(A + (size_t)(m0 + r) * lda + k0 + kc);
    }
#pragma unroll
    for (int i = 0; i < 4; i++) {
      int c = tid + 256*i; int r = c >> 3, kc = (c & 7) * 8;
      *reinterpret_cast<uint4*>(&Bs[r*72 + kc]) =
        *reinterpret_cast<const uint4*>(BT + (size_t)(n0 + r) * K + k0 + kc);
    }
    __syncthreads();
#pragma unroll
    for (int ks = 0; ks < 2; ks++) {
      short8 af[4], bf[4];
#pragma unroll
      for (int mi = 0; mi < 4; mi++)
        af[mi] = *reinterpret_cast<const short8*>(&As[(wm + mi*16 + lrow)*72 + ks*32 + lk8]);
#pragma unroll
      for (int ni = 0; ni < 4; ni++)
        bf[ni] = *reinterpret_cast<const short8*>(&Bs[(wn + ni*16 + lrow)*72 + ks*32 + lk8]);
#pragma unroll
      for (int mi = 0; mi < 4; mi++)
#pragma unroll
        for (int ni = 0; ni < 4; ni++)
          acc[mi][ni] = __builtin_amdgcn_mfma_f32_16x16x32_bf16(af[mi], bf[ni], acc[mi][ni], 0, 0, 0);
    }
  }
#pragma unroll
  for (int mi = 0; mi < 4; mi++) {
#pragma unroll
    for (int ni = 0; ni < 4; ni++) {
#pragma unroll
      for (int r = 0; r < 4; r++) {
        int gm = m0 + wm + mi*16 + (lane >> 4)*4 + r;
        int gn = n0 + wn + ni*16 + lrow;
        float v = acc[mi][ni][r] + bias[gn];
        if constexpr (EPI == EPI_QKV) {
          v *= ascale;
          size_t idx = ((size_t)((gm >> 11) * H_ + (gn >> 6)) * S_ + (gm & 2047)) * DH_ + (gn & 63);
          outh[idx] = f2bf(v);
        } else if constexpr (EPI == EPI_OPROJ) {
          size_t idx = (size_t)gm * ldo + gn;
          outf[idx] = v + resid[idx];
        } else if constexpr (EPI == EPI_GELU) {
          float gv = 0.5f * v * (1.0f + erff(v * 0.70710678118654752f));
          outh[(size_t)gm * ldo + gn] = f2bf(gv);
        } else {  // EPI_FINAL
          size_t idx = (size_t)gm * ldo + gn;
          outf[idx] = v + resid[idx];
        }
      }
    }
  }
}

// ---------------- causal flash attention v2 ----------------
// 4 waves/block, 32 q-rows per wave (128/block), 64-key tiles staged in LDS.
// Q pre-scaled by (1/sqrt(DH))*log2(e) in the Q-projection epilogue -> exp2f here.
__global__ __launch_bounds__(256) void attn_kernel(
    const unsigned short* __restrict__ q,
    const unsigned short* __restrict__ k,
    const unsigned short* __restrict__ v,
    unsigned short* __restrict__ o) {
  __shared__ __attribute__((aligned(16))) unsigned short Ks[64*72];  // [key][dh]
  __shared__ __attribute__((aligned(16))) unsigned short VT[64*72];  // [dh][key]
  __shared__ __attribute__((aligned(16))) unsigned short P[4][32*72];// per-wave [q][key]
  int tid = threadIdx.x;
  int wave = tid >> 6, lane = tid & 63;
  int lcol = lane & 15, lk8 = (lane >> 4) * 8, rbase = (lane >> 4) * 4;
  int bh = blockIdx.y;
  int bx = gridDim.x - 1 - blockIdx.x;   // heavy blocks first
  int q0 = bx * 128;
  int qw = q0 + wave * 32;
  const unsigned short* qb = q + (size_t)bh * S_ * DH_;
  const unsigned short* kb = k + (size_t)bh * S_ * DH_;
  const unsigned short* vb = v + (size_t)bh * S_ * DH_;
  unsigned short* Pw = P[wave];

  short8 qf[2][2];
#pragma unroll
  for (int u = 0; u < 2; u++)
#pragma unroll
    for (int dc = 0; dc < 2; dc++)
      qf[u][dc] = *reinterpret_cast<const short8*>(
          qb + (size_t)(qw + u*16 + lcol) * DH_ + dc*32 + lk8);

  f32x4 oacc[2][4] = {};
  float mst[2][4], lst[2][4];
#pragma unroll
  for (int u = 0; u < 2; u++)
#pragma unroll
    for (int r = 0; r < 4; r++) { mst[u][r] = -1e30f; lst[u][r] = 0.f; }

  int nt = q0 / 64 + 2;
  for (int kt = 0; kt < nt; kt++) {
    int kb0 = kt * 64;
    __syncthreads();
    { // stage K [64][64] -> Ks[key][dh], coalesced
      int r = tid >> 2, kc = (tid & 3) * 16;
      *reinterpret_cast<uint4*>(&Ks[r*72 + kc]) =
        *reinterpret_cast<const uint4*>(kb + (size_t)(kb0 + r) * DH_ + kc);
      *reinterpret_cast<uint4*>(&Ks[r*72 + kc + 8]) =
        *reinterpret_cast<const uint4*>(kb + (size_t)(kb0 + r) * DH_ + kc + 8);
    }
    { // stage V transposed -> VT[dh][key], paired-key uint writes (conflict-free)
      int kp = tid & 31, dh0 = (tid >> 5) * 8;
      union { uint4 u4; unsigned short s[8]; } a, b;
      a.u4 = *reinterpret_cast<const uint4*>(vb + (size_t)(kb0 + 2*kp)     * DH_ + dh0);
      b.u4 = *reinterpret_cast<const uint4*>(vb + (size_t)(kb0 + 2*kp + 1) * DH_ + dh0);
#pragma unroll
      for (int j = 0; j < 8; j++)
        *reinterpret_cast<unsigned*>(&VT[(dh0 + j)*72 + 2*kp]) =
            (unsigned)a.s[j] | ((unsigned)b.s[j] << 16);
    }
    __syncthreads();
    if (kb0 > qw + 31) continue;   // this wave fully masked for this tile

    // QK^T: S[32 q][64 key] in fragments sc[u][ks]
    f32x4 sc[2][4] = {};
#pragma unroll
    for (int dc = 0; dc < 2; dc++) {
      short8 kf[4];
#pragma unroll
      for (int ks = 0; ks < 4; ks++)
        kf[ks] = *reinterpret_cast<const short8*>(&Ks[(ks*16 + lcol)*72 + dc*32 + lk8]);
#pragma unroll
      for (int u = 0; u < 2; u++)
#pragma unroll
        for (int ks = 0; ks < 4; ks++)
          sc[u][ks] = __builtin_amdgcn_mfma_f32_16x16x32_bf16(qf[u][dc], kf[ks], sc[u][ks], 0, 0, 0);
    }

    bool full = (kb0 + 63 <= qw);
#pragma unroll
    for (int u = 0; u < 2; u++) {
#pragma unroll
      for (int r = 0; r < 4; r++) {
        int qr = qw + u*16 + rbase + r;
        float v0 = sc[u][0][r], v1 = sc[u][1][r], v2 = sc[u][2][r], v3 = sc[u][3][r];
        if (!full) {
          if (kb0      + lcol > qr) v0 = -1e30f;
          if (kb0 + 16 + lcol > qr) v1 = -1e30f;
          if (kb0 + 32 + lcol > qr) v2 = -1e30f;
          if (kb0 + 48 + lcol > qr) v3 = -1e30f;
        }
        float mx = fmaxf(fmaxf(v0, v1), fmaxf(v2, v3));
#pragma unroll
        for (int d = 1; d < 16; d <<= 1) mx = fmaxf(mx, __shfl_xor(mx, d));
        float mnew = fmaxf(mst[u][r], mx);
        float fac = exp2f(mst[u][r] - mnew);
        mst[u][r] = mnew;
        float p0 = exp2f(v0 - mnew), p1 = exp2f(v1 - mnew);
        float p2 = exp2f(v2 - mnew), p3 = exp2f(v3 - mnew);
        float rs = (p0 + p1) + (p2 + p3);
#pragma unroll
        for (int d = 1; d < 16; d <<= 1) rs += __shfl_xor(rs, d);
        lst[u][r] = lst[u][r] * fac + rs;
#pragma unroll
        for (int nf = 0; nf < 4; nf++) oacc[u][nf][r] *= fac;
        int prow = (u*16 + rbase + r) * 72;
        Pw[prow      + lcol] = f2bf(p0);
        Pw[prow + 16 + lcol] = f2bf(p1);
        Pw[prow + 32 + lcol] = f2bf(p2);
        Pw[prow + 48 + lcol] = f2bf(p3);
      }
    }

    // PV: O[32 q][64 dh] += P[32][64] x V[64][64]
#pragma unroll
    for (int u = 0; u < 2; u++) {
#pragma unroll
      for (int kc = 0; kc < 2; kc++) {
        short8 pa = *reinterpret_cast<const short8*>(&Pw[(u*16 + lcol)*72 + kc*32 + lk8]);
#pragma unroll
        for (int nf = 0; nf < 4; nf++) {
          short8 vf = *reinterpret_cast<const short8*>(&VT[(nf*16 + lcol)*72 + kc*32 + lk8]);
          oacc[u][nf] = __builtin_amdgcn_mfma_f32_16x16x32_bf16(pa, vf, oacc[u][nf], 0, 0, 0);
        }
      }
    }
  }

  int bb = bh / H_, hh = bh % H_;
#pragma unroll
  for (int u = 0; u < 2; u++) {
#pragma unroll
    for (int nf = 0; nf < 4; nf++) {
#pragma unroll
      for (int r = 0; r < 4; r++) {
        float val = oacc[u][nf][r] / lst[u][r];
        int qr = qw + u*16 + rbase + r;
        int dh = nf*16 + lcol;
        o[((size_t)(bb * S_ + qr)) * D_ + hh * DH_ + dh] = f2bf(val);
      }
    }
  }
}

extern "C" void kernel_launch(void* const* d_in, const int* in_sizes, int n_in,
                              void* d_out, int out_size, void* d_ws, size_t ws_size,
                              hipStream_t stream) {
  (void)in_sizes; (void)n_in; (void)out_size; (void)ws_size;
  const float* x    = (const float*)d_in[0];
  const float* ln1g = (const float*)d_in[1];
  const float* ln1b = (const float*)d_in[2];
  const float* Wq   = (const float*)d_in[3];
  const float* bq   = (const float*)d_in[4];
  const float* Wk   = (const float*)d_in[5];
  const float* bk   = (const float*)d_in[6];
  const float* Wv   = (const float*)d_in[7];
  const float* bv   = (const float*)d_in[8];
  const float* Wo   = (const float*)d_in[9];
  const float* bo   = (const float*)d_in[10];
  const float* ln2g = (const float*)d_in[11];
  const float* ln2b = (const float*)d_in[12];
  const float* W1   = (const float*)d_in[13];
  const float* b1   = (const float*)d_in[14];
  const float* W2   = (const float*)d_in[15];
  const float* b2   = (const float*)d_in[16];
  float* out = (float*)d_out;

  char* ws = (char*)d_ws;
  size_t off = 0;
  auto alloc = [&](size_t bytes) {
    char* p = ws + off;
    off += (bytes + 255) & ~(size_t)255;
    return p;
  };
  unsigned short* WqT = (unsigned short*)alloc((size_t)D_*D_*2);
  unsigned short* WkT = (unsigned short*)alloc((size_t)D_*D_*2);
  unsigned short* WvT = (unsigned short*)alloc((size_t)D_*D_*2);
  unsigned short* WoT = (unsigned short*)alloc((size_t)D_*D_*2);
  unsigned short* W1T = (unsigned short*)alloc((size_t)D_*FF_*2);
  unsigned short* W2T = (unsigned short*)alloc((size_t)FF_*D_*2);
  unsigned short* h   = (unsigned short*)alloc((size_t)B_*S_*D_*2);
  unsigned short* qb  = (unsigned short*)alloc((size_t)B_*S_*D_*2);
  unsigned short* kbf = (unsigned short*)alloc((size_t)B_*S_*D_*2);
  unsigned short* vbf = (unsigned short*)alloc((size_t)B_*S_*D_*2);
  unsigned short* ob  = (unsigned short*)alloc((size_t)B_*S_*D_*2);
  unsigned short* ffb = qb;  // reuse q/k/v/o region (exactly 4*B*S*D*2 = B*S*FF*2 bytes)
  unsigned short* h2  = h;   // reuse h

  const float qscale = 0.125f * 1.4426950408889634f;  // 1/sqrt(DH) * log2(e)

  dim3 tb(32, 8);
  transpose_cast_kernel<<<dim3(D_/32,  D_/32),  tb, 0, stream>>>(Wq, WqT, D_,  D_);
  transpose_cast_kernel<<<dim3(D_/32,  D_/32),  tb, 0, stream>>>(Wk, WkT, D_,  D_);
  transpose_cast_kernel<<<dim3(D_/32,  D_/32),  tb, 0, stream>>>(Wv, WvT, D_,  D_);
  transpose_cast_kernel<<<dim3(D_/32,  D_/32),  tb, 0, stream>>>(Wo, WoT, D_,  D_);
  transpose_cast_kernel<<<dim3(D_/32,  FF_/32), tb, 0, stream>>>(W1, W1T, D_,  FF_);
  transpose_cast_kernel<<<dim3(FF_/32, D_/32),  tb, 0, stream>>>(W2, W2T, FF_, D_);

  layernorm_kernel<<<(B_*S_)/4, 256, 0, stream>>>(x, ln1g, ln1b, h);

  gemm_kernel<EPI_QKV><<<dim3(D_/128, (B_*S_)/128), 256, 0, stream>>>(
      h, D_, WqT, D_, bq, nullptr, nullptr, qb, D_, qscale);
  gemm_kernel<EPI_QKV><<<dim3(D_/128, (B_*S_)/128), 256, 0, stream>>>(
      h, D_, WkT, D_, bk, nullptr, nullptr, kbf, D_, 1.0f);
  gemm_kernel<EPI_QKV><<<dim3(D_/128, (B_*S_)/128), 256, 0, stream>>>(
      h, D_, WvT, D_, bv, nullptr, nullptr, vbf, D_, 1.0f);

  attn_kernel<<<dim3(S_/128, B_*H_), 256, 0, stream>>>(qb, kbf, vbf, ob);

  gemm_kernel<EPI_OPROJ><<<dim3(D_/128, (B_*S_)/128), 256, 0, stream>>>(
      ob, D_, WoT, D_, bo, x, out, nullptr, D_, 1.0f);

  layernorm_kernel<<<(B_*S_)/4, 256, 0, stream>>>(out, ln2g, ln2b, h2);

  gemm_kernel<EPI_GELU><<<dim3(FF_/128, (B_*S_)/128), 256, 0, stream>>>(
      h2, D_, W1T, D_, b1, nullptr, nullptr, ffb, FF_, 1.0f);

  gemm_kernel<EPI_FINAL><<<dim3(D_/128, (B_*S_)/128), 256, 0, stream>>>(
      ffb, FF_, W2T, FF_, b2, out, out, nullptr, D_, 1.0f);
}

// Round 3
// 426.007 us; speedup vs baseline: 1.5649x; 1.2702x over previous
//
#include <hip/hip_runtime.h>
#include <math.h>

#define B_ 4
#define S_ 2048
#define D_ 768
#define H_ 12
#define DH_ 64
#define FF_ 3072

using short8  = __attribute__((ext_vector_type(8))) short;
using f32x4   = __attribute__((ext_vector_type(4))) float;
using f32x16  = __attribute__((ext_vector_type(16))) float;
using float4v = __attribute__((ext_vector_type(4))) float;
using ushort4v= __attribute__((ext_vector_type(4))) unsigned short;

__device__ __forceinline__ unsigned short f2bf(float f) {
  unsigned u = __builtin_bit_cast(unsigned, f);
  u += 0x7FFFu + ((u >> 16) & 1u);   // round-to-nearest-even
  return (unsigned short)(u >> 16);
}

__device__ __forceinline__ void gload16(const void* g, void* l) {
  __builtin_amdgcn_global_load_lds(
      (const __attribute__((address_space(1))) unsigned*)g,
      (__attribute__((address_space(3))) unsigned*)l, 16, 0, 0);
}

// ---------------- weight transpose + cast: in [K][N] f32 -> out [N][K] bf16 ----------------
__global__ __launch_bounds__(256) void transpose_cast_kernel(
    const float* __restrict__ in, unsigned short* __restrict__ out, int K, int N) {
  __shared__ float tile[32][33];
  int k0 = blockIdx.x * 32, n0 = blockIdx.y * 32;
  int tx = threadIdx.x, ty = threadIdx.y;
#pragma unroll
  for (int i = 0; i < 4; i++)
    tile[ty + 8*i][tx] = in[(size_t)(k0 + ty + 8*i) * N + n0 + tx];
  __syncthreads();
#pragma unroll
  for (int i = 0; i < 4; i++)
    out[(size_t)(n0 + ty + 8*i) * K + k0 + tx] = f2bf(tile[tx][ty + 8*i]);
}

// ---------------- bias concat: [bq | bk | bv] -> 2304 floats ----------------
__global__ void bias_cat_kernel(const float* __restrict__ bq, const float* __restrict__ bk,
                                const float* __restrict__ bv, float* __restrict__ dst) {
  int i = blockIdx.x * 256 + threadIdx.x;
  if (i >= 3 * D_) return;
  float v;
  if (i < D_)            v = bq[i];
  else if (i < 2 * D_)   v = bk[i - D_];
  else                   v = bv[i - 2 * D_];
  dst[i] = v;
}

// ---------------- LayerNorm: fp32 in -> bf16 out, one wave per row of 768 ----------------
__global__ __launch_bounds__(256) void layernorm_kernel(
    const float* __restrict__ x, const float* __restrict__ g,
    const float* __restrict__ b, unsigned short* __restrict__ out) {
  int wave = threadIdx.x >> 6, lane = threadIdx.x & 63;
  int row = blockIdx.x * 4 + wave;
  const float* xr = x + (size_t)row * D_;
  float4v v[3];
  float sum = 0.f, sq = 0.f;
#pragma unroll
  for (int i = 0; i < 3; i++) {
    v[i] = reinterpret_cast<const float4v*>(xr)[lane + 64*i];
#pragma unroll
    for (int j = 0; j < 4; j++) { sum += v[i][j]; sq += v[i][j]*v[i][j]; }
  }
#pragma unroll
  for (int d = 1; d < 64; d <<= 1) { sum += __shfl_xor(sum, d); sq += __shfl_xor(sq, d); }
  float mu   = sum * (1.0f / D_);
  float var  = sq  * (1.0f / D_) - mu * mu;
  float rstd = rsqrtf(var + 1e-5f);
  unsigned short* orow = out + (size_t)row * D_;
#pragma unroll
  for (int i = 0; i < 3; i++) {
    int idx = (lane + 64*i) * 4;
    ushort4v o;
#pragma unroll
    for (int j = 0; j < 4; j++)
      o[j] = f2bf((v[i][j] - mu) * rstd * g[idx + j] + b[idx + j]);
    *reinterpret_cast<ushort4v*>(orow + idx) = o;
  }
}

// ---------------- bf16 MFMA GEMM, 128x128 tile, BK=64, 4 waves, global_load_lds ----------------
#define EPI_QKV   0
#define EPI_OPROJ 1
#define EPI_GELU  2
#define EPI_FINAL 3

template<int EPI>
__global__ __launch_bounds__(256) void gemm_kernel(
    const unsigned short* __restrict__ A, int lda,
    const unsigned short* __restrict__ BT, int K,
    const float* __restrict__ bias,
    const float* __restrict__ resid,
    float* __restrict__ outf,
    unsigned short* __restrict__ outh,
    int ldo, float ascale) {
  __shared__ __attribute__((aligned(16))) unsigned short As[128*64];
  __shared__ __attribute__((aligned(16))) unsigned short Bs[128*64];
  int tid = threadIdx.x;
  int wave = tid >> 6, lane = tid & 63;
  int lrow = lane & 15, lk8 = (lane >> 4) * 8;
  int m0 = blockIdx.y * 128, n0 = blockIdx.x * 128;
  int wm = (wave >> 1) * 64, wn = (wave & 1) * 64;
  int srow = wave * 32 + (lane >> 3);   // staging row (lane part)
  int scol = (lane & 7) * 8;            // staging col (elems)
  f32x4 acc[4][4] = {};
  for (int k0 = 0; k0 < K; k0 += 64) {
    __syncthreads();
#pragma unroll
    for (int i = 0; i < 4; i++) {
      gload16(A  + (size_t)(m0 + srow + i*8) * lda + k0 + scol, &As[(wave*32 + i*8) * 64]);
      gload16(BT + (size_t)(n0 + srow + i*8) * K   + k0 + scol, &Bs[(wave*32 + i*8) * 64]);
    }
    __syncthreads();
#pragma unroll
    for (int ks = 0; ks < 2; ks++) {
      short8 af[4], bf[4];
#pragma unroll
      for (int mi = 0; mi < 4; mi++)
        af[mi] = *reinterpret_cast<const short8*>(&As[(wm + mi*16 + lrow)*64 + ks*32 + lk8]);
#pragma unroll
      for (int ni = 0; ni < 4; ni++)
        bf[ni] = *reinterpret_cast<const short8*>(&Bs[(wn + ni*16 + lrow)*64 + ks*32 + lk8]);
#pragma unroll
      for (int mi = 0; mi < 4; mi++)
#pragma unroll
        for (int ni = 0; ni < 4; ni++)
          acc[mi][ni] = __builtin_amdgcn_mfma_f32_16x16x32_bf16(af[mi], bf[ni], acc[mi][ni], 0, 0, 0);
    }
  }
  int pproj = (EPI == EPI_QKV) ? (n0 / D_) : 0;  // uniform per block (128 | 768)
#pragma unroll
  for (int mi = 0; mi < 4; mi++) {
#pragma unroll
    for (int ni = 0; ni < 4; ni++) {
#pragma unroll
      for (int r = 0; r < 4; r++) {
        int gm = m0 + wm + mi*16 + (lane >> 4)*4 + r;
        int gn = n0 + wn + ni*16 + lrow;
        float v = acc[mi][ni][r] + bias[gn];
        if constexpr (EPI == EPI_QKV) {
          if (gn < D_) v *= ascale;   // Q pre-scale: 1/sqrt(DH)*log2(e)
          int c = gn - pproj * D_;
          size_t idx = (((size_t)(pproj*B_ + (gm >> 11)) * H_ + (c >> 6)) * S_ + (gm & 2047)) * DH_ + (c & 63);
          outh[idx] = f2bf(v);
        } else if constexpr (EPI == EPI_OPROJ) {
          size_t idx = (size_t)gm * ldo + gn;
          outf[idx] = v + resid[idx];
        } else if constexpr (EPI == EPI_GELU) {
          float gv = 0.5f * v * (1.0f + erff(v * 0.70710678118654752f));
          outh[(size_t)gm * ldo + gn] = f2bf(gv);
        } else {  // EPI_FINAL
          size_t idx = (size_t)gm * ldo + gn;
          outf[idx] = v + resid[idx];
        }
      }
    }
  }
}

// ---------------- causal flash attention v3: swapped-operand 32x32x16 ----------------
// 4 waves x 32 q-rows = 128 q/block, 64-key tiles. Each lane owns ONE q-row
// (col = lane&31): softmax is lane-local regs + one shfl_xor(.,32).
// QK^T: S^T = mfma(A=K, B=Q^T)  -> C col=q, row=key
// PV  : O^T = mfma(A=V^T, B=P^T)-> C col=q, row=dh   (rescale lane-local)
__global__ __launch_bounds__(256) void attn_kernel(
    const unsigned short* __restrict__ q,
    const unsigned short* __restrict__ k,
    const unsigned short* __restrict__ v,
    unsigned short* __restrict__ o) {
  __shared__ __attribute__((aligned(16))) unsigned short Ks[64*64];   // [key][dh] swizzled
  __shared__ __attribute__((aligned(16))) unsigned short VT[64*64];   // [dh][key] swizzled
  __shared__ __attribute__((aligned(16))) unsigned short P2[4][32*64];// per-wave [q][key] swizzled
  int tid = threadIdx.x;
  int wave = tid >> 6, lane = tid & 63;
  int ql = lane & 31, hi = lane >> 5;
  int bh = blockIdx.y;
  int bx = gridDim.x - 1 - blockIdx.x;   // heavy blocks first
  int q0 = bx * 128;
  int qw = q0 + wave * 32;
  int myq = qw + ql;
  const unsigned short* qb = q + (size_t)bh * S_ * DH_;
  const unsigned short* kb = k + (size_t)bh * S_ * DH_;
  const unsigned short* vb = v + (size_t)bh * S_ * DH_;
  unsigned short* Pw = P2[wave];
  int swq = (ql & 7) << 4;

  // Q fragments (B-operand): lane -> Q[myq][dblk*16 + hi*8 .. +8)
  short8 qf[4];
#pragma unroll
  for (int dblk = 0; dblk < 4; dblk++)
    qf[dblk] = *reinterpret_cast<const short8*>(qb + (size_t)myq * DH_ + dblk*16 + hi*8);

  f32x16 oaccT[2] = {};   // O^T: [dhblk]; col=q(lane), row=dh(reg)
  float mst = -1e30f, lst = 0.f;

  int nt = q0 / 64 + 2;
  for (int kt = 0; kt < nt; kt++) {
    int kb0 = kt * 64;
    __syncthreads();
    { // stage K [64][64] -> Ks swizzled (byte col ^ ((row&7)<<4))
      int r = tid >> 2;
      int cb = (tid & 3) * 32;
      int sw = (r & 7) << 4;
      const unsigned short* src = kb + (size_t)(kb0 + r) * DH_ + (tid & 3) * 16;
      uint4 a = *reinterpret_cast<const uint4*>(src);
      uint4 b = *reinterpret_cast<const uint4*>(src + 8);
      *reinterpret_cast<uint4*>(&Ks[(r*128 + (cb ^ sw)) >> 1]) = a;
      *reinterpret_cast<uint4*>(&Ks[(r*128 + ((cb + 16) ^ sw)) >> 1]) = b;
    }
    { // stage V transposed -> VT[dh][key] swizzled, paired-key u32 writes
      int kp = tid & 31, dh0 = (tid >> 5) * 8;
      union { uint4 u4; unsigned short s[8]; } a, b;
      a.u4 = *reinterpret_cast<const uint4*>(vb + (size_t)(kb0 + 2*kp)     * DH_ + dh0);
      b.u4 = *reinterpret_cast<const uint4*>(vb + (size_t)(kb0 + 2*kp + 1) * DH_ + dh0);
#pragma unroll
      for (int j = 0; j < 8; j++) {
        int row = dh0 + j;
        int sw = (row & 7) << 4;
        *reinterpret_cast<unsigned*>(&VT[(row*128 + ((4*kp) ^ sw)) >> 1]) =
            (unsigned)a.s[j] | ((unsigned)b.s[j] << 16);
      }
    }
    __syncthreads();
    if (kb0 > qw + 31) continue;   // wave fully masked

    // QK^T: sc[blk] = S^T fragment, lane owns q=myq, regs = 16 keys each half
    f32x16 sc[2] = {};
#pragma unroll
    for (int dblk = 0; dblk < 4; dblk++) {
#pragma unroll
      for (int blk = 0; blk < 2; blk++) {
        int row = blk*32 + ql;
        int sw = (row & 7) << 4;
        short8 kf = *reinterpret_cast<const short8*>(
            &Ks[(row*128 + (((unsigned)(dblk*32 + hi*16)) ^ sw)) >> 1]);
        sc[blk] = __builtin_amdgcn_mfma_f32_32x32x16_bf16(kf, qf[dblk], sc[blk], 0, 0, 0);
      }
    }

    bool full = (kb0 + 63 <= qw);
    if (!full) {
#pragma unroll
      for (int blk = 0; blk < 2; blk++)
#pragma unroll
        for (int r = 0; r < 16; r++) {
          int key = kb0 + blk*32 + (r & 3) + 8*(r >> 2) + 4*hi;
          if (key > myq) sc[blk][r] = -1e30f;
        }
    }

    // lane-local row max (4 partial chains) + cross-half
    float pm0 = -1e30f, pm1 = -1e30f, pm2 = -1e30f, pm3 = -1e30f;
#pragma unroll
    for (int blk = 0; blk < 2; blk++)
#pragma unroll
      for (int g = 0; g < 4; g++) {
        pm0 = fmaxf(pm0, sc[blk][4*g]);
        pm1 = fmaxf(pm1, sc[blk][4*g+1]);
        pm2 = fmaxf(pm2, sc[blk][4*g+2]);
        pm3 = fmaxf(pm3, sc[blk][4*g+3]);
      }
    float mx = fmaxf(fmaxf(pm0, pm1), fmaxf(pm2, pm3));
    mx = fmaxf(mx, __shfl_xor(mx, 32));
    float mnew = fmaxf(mst, mx);
    float fac = exp2f(mst - mnew);
    // p = exp2(s - m), lane-local sum
    float ps0 = 0.f, ps1 = 0.f, ps2 = 0.f, ps3 = 0.f;
#pragma unroll
    for (int blk = 0; blk < 2; blk++)
#pragma unroll
      for (int g = 0; g < 4; g++) {
        float p0 = exp2f(sc[blk][4*g]   - mnew);
        float p1 = exp2f(sc[blk][4*g+1] - mnew);
        float p2 = exp2f(sc[blk][4*g+2] - mnew);
        float p3 = exp2f(sc[blk][4*g+3] - mnew);
        sc[blk][4*g] = p0; sc[blk][4*g+1] = p1; sc[blk][4*g+2] = p2; sc[blk][4*g+3] = p3;
        ps0 += p0; ps1 += p1; ps2 += p2; ps3 += p3;
      }
    float rs = (ps0 + ps1) + (ps2 + ps3);
    rs += __shfl_xor(rs, 32);
    lst = lst * fac + rs;
    mst = mnew;
#pragma unroll
    for (int db = 0; db < 2; db++)
#pragma unroll
      for (int r = 0; r < 16; r++) oaccT[db][r] *= fac;

    // pack P -> per-wave LDS [q][key], swizzled; 8x b64 writes
#pragma unroll
    for (int blk = 0; blk < 2; blk++)
#pragma unroll
      for (int g = 0; g < 4; g++) {
        unsigned lo  = (unsigned)f2bf(sc[blk][4*g])   | ((unsigned)f2bf(sc[blk][4*g+1]) << 16);
        unsigned hi2 = (unsigned)f2bf(sc[blk][4*g+2]) | ((unsigned)f2bf(sc[blk][4*g+3]) << 16);
        int cbyte = (blk*64 + g*16 + hi*8) ^ swq;
        uint2 val; val.x = lo; val.y = hi2;
        *reinterpret_cast<uint2*>(&Pw[(ql*128 + cbyte) >> 1]) = val;
      }

    // PV: O^T += mfma(A=V^T, B=P^T)
#pragma unroll
    for (int ks = 0; ks < 4; ks++) {
      int cb = ks*32 + hi*16;
      short8 pa = *reinterpret_cast<const short8*>(&Pw[(ql*128 + (cb ^ swq)) >> 1]);
#pragma unroll
      for (int db = 0; db < 2; db++) {
        int row = db*32 + ql;
        int sw = (row & 7) << 4;
        short8 vf = *reinterpret_cast<const short8*>(&VT[(row*128 + (cb ^ sw)) >> 1]);
        oaccT[db] = __builtin_amdgcn_mfma_f32_32x32x16_bf16(vf, pa, oaccT[db], 0, 0, 0);
      }
    }
  }

  // epilogue: lane owns q-column; divide by l, write paired bf16
  int bb = bh / H_, hh = bh % H_;
  float inv = 1.0f / lst;
  unsigned short* ob = o + ((size_t)(bb * S_ + myq)) * D_ + hh * DH_;
#pragma unroll
  for (int db = 0; db < 2; db++)
#pragma unroll
    for (int g = 0; g < 8; g++) {
      int r = 2 * g;
      int dh = db*32 + (r & 3) + 8*(r >> 2) + 4*hi;
      unsigned pk = (unsigned)f2bf(oaccT[db][r] * inv) |
                    ((unsigned)f2bf(oaccT[db][r+1] * inv) << 16);
      *reinterpret_cast<unsigned*>(ob + dh) = pk;
    }
}

extern "C" void kernel_launch(void* const* d_in, const int* in_sizes, int n_in,
                              void* d_out, int out_size, void* d_ws, size_t ws_size,
                              hipStream_t stream) {
  (void)in_sizes; (void)n_in; (void)out_size; (void)ws_size;
  const float* x    = (const float*)d_in[0];
  const float* ln1g = (const float*)d_in[1];
  const float* ln1b = (const float*)d_in[2];
  const float* Wq   = (const float*)d_in[3];
  const float* bq   = (const float*)d_in[4];
  const float* Wk   = (const float*)d_in[5];
  const float* bk   = (const float*)d_in[6];
  const float* Wv   = (const float*)d_in[7];
  const float* bv   = (const float*)d_in[8];
  const float* Wo   = (const float*)d_in[9];
  const float* bo   = (const float*)d_in[10];
  const float* ln2g = (const float*)d_in[11];
  const float* ln2b = (const float*)d_in[12];
  const float* W1   = (const float*)d_in[13];
  const float* b1   = (const float*)d_in[14];
  const float* W2   = (const float*)d_in[15];
  const float* b2   = (const float*)d_in[16];
  float* out = (float*)d_out;

  char* ws = (char*)d_ws;
  size_t off = 0;
  auto alloc = [&](size_t bytes) {
    char* p = ws + off;
    off += (bytes + 255) & ~(size_t)255;
    return p;
  };
  // NOTE: WqT/WkT/WvT contiguous => one [2304][768] B-matrix for fused QKV.
  unsigned short* WqT = (unsigned short*)alloc((size_t)D_*D_*2);
  unsigned short* WkT = (unsigned short*)alloc((size_t)D_*D_*2);
  unsigned short* WvT = (unsigned short*)alloc((size_t)D_*D_*2);
  unsigned short* WoT = (unsigned short*)alloc((size_t)D_*D_*2);
  unsigned short* W1T = (unsigned short*)alloc((size_t)D_*FF_*2);
  unsigned short* W2T = (unsigned short*)alloc((size_t)FF_*D_*2);
  unsigned short* h   = (unsigned short*)alloc((size_t)B_*S_*D_*2);
  // q/k/v contiguous => fused QKV epilogue scatters into one region.
  unsigned short* qb  = (unsigned short*)alloc((size_t)B_*S_*D_*2);
  unsigned short* kbf = (unsigned short*)alloc((size_t)B_*S_*D_*2);
  unsigned short* vbf = (unsigned short*)alloc((size_t)B_*S_*D_*2);
  unsigned short* ob  = (unsigned short*)alloc((size_t)B_*S_*D_*2);
  float* bias_cat     = (float*)alloc((size_t)3*D_*4);
  unsigned short* ffb = qb;  // reuse q/k/v region (4*B*S*D*2 >= B*S*FF*2)
  unsigned short* h2  = h;   // reuse h

  const float qscale = 0.125f * 1.4426950408889634f;  // 1/sqrt(DH) * log2(e)

  dim3 tb(32, 8);
  transpose_cast_kernel<<<dim3(D_/32,  D_/32),  tb, 0, stream>>>(Wq, WqT, D_,  D_);
  transpose_cast_kernel<<<dim3(D_/32,  D_/32),  tb, 0, stream>>>(Wk, WkT, D_,  D_);
  transpose_cast_kernel<<<dim3(D_/32,  D_/32),  tb, 0, stream>>>(Wv, WvT, D_,  D_);
  transpose_cast_kernel<<<dim3(D_/32,  D_/32),  tb, 0, stream>>>(Wo, WoT, D_,  D_);
  transpose_cast_kernel<<<dim3(D_/32,  FF_/32), tb, 0, stream>>>(W1, W1T, D_,  FF_);
  transpose_cast_kernel<<<dim3(FF_/32, D_/32),  tb, 0, stream>>>(W2, W2T, FF_, D_);
  bias_cat_kernel<<<9, 256, 0, stream>>>(bq, bk, bv, bias_cat);

  layernorm_kernel<<<(B_*S_)/4, 256, 0, stream>>>(x, ln1g, ln1b, h);

  // fused QKV: one GEMM, N = 2304
  gemm_kernel<EPI_QKV><<<dim3(3*D_/128, (B_*S_)/128), 256, 0, stream>>>(
      h, D_, WqT, D_, bias_cat, nullptr, nullptr, qb, D_, qscale);

  attn_kernel<<<dim3(S_/128, B_*H_), 256, 0, stream>>>(qb, kbf, vbf, ob);

  gemm_kernel<EPI_OPROJ><<<dim3(D_/128, (B_*S_)/128), 256, 0, stream>>>(
      ob, D_, WoT, D_, bo, x, out, nullptr, D_, 1.0f);

  layernorm_kernel<<<(B_*S_)/4, 256, 0, stream>>>(out, ln2g, ln2b, h2);

  gemm_kernel<EPI_GELU><<<dim3(FF_/128, (B_*S_)/128), 256, 0, stream>>>(
      h2, D_, W1T, D_, b1, nullptr, nullptr, ffb, FF_, 1.0f);

  gemm_kernel<EPI_FINAL><<<dim3(D_/128, (B_*S_)/128), 256, 0, stream>>>(
      ffb, FF_, W2T, FF_, b2, out, out, nullptr, D_, 1.0f);
}

// Round 4
// 365.315 us; speedup vs baseline: 1.8249x; 1.1661x over previous
//
#include <hip/hip_runtime.h>
#include <math.h>

#define B_ 4
#define S_ 2048
#define D_ 768
#define H_ 12
#define DH_ 64
#define FF_ 3072

using short8  = __attribute__((ext_vector_type(8))) short;
using f32x4   = __attribute__((ext_vector_type(4))) float;
using f32x16  = __attribute__((ext_vector_type(16))) float;
using float4v = __attribute__((ext_vector_type(4))) float;
using ushort4v= __attribute__((ext_vector_type(4))) unsigned short;

__device__ __forceinline__ unsigned short f2bf(float f) {
  unsigned u = __builtin_bit_cast(unsigned, f);
  u += 0x7FFFu + ((u >> 16) & 1u);   // round-to-nearest-even
  return (unsigned short)(u >> 16);
}

__device__ __forceinline__ unsigned cvt_pk_bf16(float a, float b) {
  unsigned r;
  asm("v_cvt_pk_bf16_f32 %0, %1, %2" : "=v"(r) : "v"(a), "v"(b));
  return r;   // lo = bf16(a), hi = bf16(b)
}

__device__ __forceinline__ void gload16(const void* g, void* l) {
  __builtin_amdgcn_global_load_lds(
      (const __attribute__((address_space(1))) unsigned*)g,
      (__attribute__((address_space(3))) unsigned*)l, 16, 0, 0);
}

// ---------------- weight transpose + cast: in [K][N] f32 -> out [N][K] bf16 ----------------
__global__ __launch_bounds__(256) void transpose_cast_kernel(
    const float* __restrict__ in, unsigned short* __restrict__ out, int K, int N) {
  __shared__ float tile[32][33];
  int k0 = blockIdx.x * 32, n0 = blockIdx.y * 32;
  int tx = threadIdx.x, ty = threadIdx.y;
#pragma unroll
  for (int i = 0; i < 4; i++)
    tile[ty + 8*i][tx] = in[(size_t)(k0 + ty + 8*i) * N + n0 + tx];
  __syncthreads();
#pragma unroll
  for (int i = 0; i < 4; i++)
    out[(size_t)(n0 + ty + 8*i) * K + k0 + tx] = f2bf(tile[tx][ty + 8*i]);
}

// ---------------- bias concat: [bq | bk | bv] -> 2304 floats ----------------
__global__ void bias_cat_kernel(const float* __restrict__ bq, const float* __restrict__ bk,
                                const float* __restrict__ bv, float* __restrict__ dst) {
  int i = blockIdx.x * 256 + threadIdx.x;
  if (i >= 3 * D_) return;
  float v;
  if (i < D_)            v = bq[i];
  else if (i < 2 * D_)   v = bk[i - D_];
  else                   v = bv[i - 2 * D_];
  dst[i] = v;
}

// ---------------- LayerNorm: fp32 in -> bf16 out, one wave per row of 768 ----------------
__global__ __launch_bounds__(256) void layernorm_kernel(
    const float* __restrict__ x, const float* __restrict__ g,
    const float* __restrict__ b, unsigned short* __restrict__ out) {
  int wave = threadIdx.x >> 6, lane = threadIdx.x & 63;
  int row = blockIdx.x * 4 + wave;
  const float* xr = x + (size_t)row * D_;
  float4v v[3];
  float sum = 0.f, sq = 0.f;
#pragma unroll
  for (int i = 0; i < 3; i++) {
    v[i] = reinterpret_cast<const float4v*>(xr)[lane + 64*i];
#pragma unroll
    for (int j = 0; j < 4; j++) { sum += v[i][j]; sq += v[i][j]*v[i][j]; }
  }
#pragma unroll
  for (int d = 1; d < 64; d <<= 1) { sum += __shfl_xor(sum, d); sq += __shfl_xor(sq, d); }
  float mu   = sum * (1.0f / D_);
  float var  = sq  * (1.0f / D_) - mu * mu;
  float rstd = rsqrtf(var + 1e-5f);
  unsigned short* orow = out + (size_t)row * D_;
#pragma unroll
  for (int i = 0; i < 3; i++) {
    int idx = (lane + 64*i) * 4;
    ushort4v o;
#pragma unroll
    for (int j = 0; j < 4; j++)
      o[j] = f2bf((v[i][j] - mu) * rstd * g[idx + j] + b[idx + j]);
    *reinterpret_cast<ushort4v*>(orow + idx) = o;
  }
}

// ---------------- bf16 MFMA GEMM, 128x128 tile, BK=64, 4 waves, global_load_lds ----------------
#define EPI_QKV   0
#define EPI_OPROJ 1
#define EPI_GELU  2
#define EPI_FINAL 3

template<int EPI>
__global__ __launch_bounds__(256) void gemm_kernel(
    const unsigned short* __restrict__ A, int lda,
    const unsigned short* __restrict__ BT, int K,
    const float* __restrict__ bias,
    const float* __restrict__ resid,
    float* __restrict__ outf,
    unsigned short* __restrict__ outh,
    int ldo, float ascale) {
  __shared__ __attribute__((aligned(16))) unsigned short As[128*64];
  __shared__ __attribute__((aligned(16))) unsigned short Bs[128*64];
  int tid = threadIdx.x;
  int wave = tid >> 6, lane = tid & 63;
  int lrow = lane & 15, lk8 = (lane >> 4) * 8;
  int m0 = blockIdx.y * 128, n0 = blockIdx.x * 128;
  int wm = (wave >> 1) * 64, wn = (wave & 1) * 64;
  int srow = wave * 32 + (lane >> 3);   // staging row (lane part)
  int scol = (lane & 7) * 8;            // staging col (elems)
  f32x4 acc[4][4] = {};
  for (int k0 = 0; k0 < K; k0 += 64) {
    __syncthreads();
#pragma unroll
    for (int i = 0; i < 4; i++) {
      gload16(A  + (size_t)(m0 + srow + i*8) * lda + k0 + scol, &As[(wave*32 + i*8) * 64]);
      gload16(BT + (size_t)(n0 + srow + i*8) * K   + k0 + scol, &Bs[(wave*32 + i*8) * 64]);
    }
    __syncthreads();
#pragma unroll
    for (int ks = 0; ks < 2; ks++) {
      short8 af[4], bf[4];
#pragma unroll
      for (int mi = 0; mi < 4; mi++)
        af[mi] = *reinterpret_cast<const short8*>(&As[(wm + mi*16 + lrow)*64 + ks*32 + lk8]);
#pragma unroll
      for (int ni = 0; ni < 4; ni++)
        bf[ni] = *reinterpret_cast<const short8*>(&Bs[(wn + ni*16 + lrow)*64 + ks*32 + lk8]);
#pragma unroll
      for (int mi = 0; mi < 4; mi++)
#pragma unroll
        for (int ni = 0; ni < 4; ni++)
          acc[mi][ni] = __builtin_amdgcn_mfma_f32_16x16x32_bf16(af[mi], bf[ni], acc[mi][ni], 0, 0, 0);
    }
  }
  int pproj = (EPI == EPI_QKV) ? (n0 / D_) : 0;  // uniform per block (128 | 768)
#pragma unroll
  for (int mi = 0; mi < 4; mi++) {
#pragma unroll
    for (int ni = 0; ni < 4; ni++) {
#pragma unroll
      for (int r = 0; r < 4; r++) {
        int gm = m0 + wm + mi*16 + (lane >> 4)*4 + r;
        int gn = n0 + wn + ni*16 + lrow;
        float v = acc[mi][ni][r] + bias[gn];
        if constexpr (EPI == EPI_QKV) {
          if (gn < D_) v *= ascale;   // Q pre-scale: 1/sqrt(DH)*log2(e)
          int c = gn - pproj * D_;
          size_t idx = (((size_t)(pproj*B_ + (gm >> 11)) * H_ + (c >> 6)) * S_ + (gm & 2047)) * DH_ + (c & 63);
          outh[idx] = f2bf(v);
        } else if constexpr (EPI == EPI_OPROJ) {
          size_t idx = (size_t)gm * ldo + gn;
          outf[idx] = v + resid[idx];
        } else if constexpr (EPI == EPI_GELU) {
          float gv = 0.5f * v * (1.0f + erff(v * 0.70710678118654752f));
          outh[(size_t)gm * ldo + gn] = f2bf(gv);
        } else {  // EPI_FINAL
          size_t idx = (size_t)gm * ldo + gn;
          outf[idx] = v + resid[idx];
        }
      }
    }
  }
}

// ---------------- causal flash attention v4 ----------------
// Fold-paired uniform blocks (q-tiles bx & 15-bx), XCD-aware bh mapping,
// double-buffered K/V with early-issue reg staging, swapped-operand 32x32x16,
// lane-local softmax + defer-max (THR=8 in log2 domain), cvt_pk bf16 packing.
__global__ __launch_bounds__(256) void attn_kernel(
    const unsigned short* __restrict__ q,
    const unsigned short* __restrict__ k,
    const unsigned short* __restrict__ v,
    unsigned short* __restrict__ o) {
  __shared__ __attribute__((aligned(16))) unsigned short Ks[2][64*64];  // [key][dh] swizzled
  __shared__ __attribute__((aligned(16))) unsigned short VT[2][64*64];  // [dh][key] swizzled
  __shared__ __attribute__((aligned(16))) unsigned short P2[4][32*64];  // per-wave [q][key] swizzled
  int tid = threadIdx.x;
  int wave = tid >> 6, lane = tid & 63;
  int ql = lane & 31, hi = lane >> 5;
  // 384 blocks: xcd = bid%8 hosts 6 bh; all 8 fold-blocks of a bh on one XCD.
  int bid = blockIdx.x;
  int xcd = bid & 7, kk = bid >> 3;
  int bx = kk & 7;                 // fold index 0..7 -> q-tiles {15-bx, bx}
  int bh = (kk >> 3) * 8 + xcd;    // 0..47
  const unsigned short* qb = q + (size_t)bh * S_ * DH_;
  const unsigned short* kb = k + (size_t)bh * S_ * DH_;
  const unsigned short* vb = v + (size_t)bh * S_ * DH_;
  unsigned short* Pw = P2[wave];
  int swq = (ql & 7) << 4;
  int bb = bh / H_, hh = bh % H_;

  // staging geometry
  int sr = tid >> 2;                 // K row 0..63
  int sc16 = (tid & 3) * 16;         // K col (elems)
  int kp = tid & 31, dh0 = (tid >> 5) * 8;
  uint4 krA, krB, vrA, vrB;

  auto LOADR = [&](int kb0) {
    const unsigned short* ksrc = kb + (size_t)(kb0 + sr) * DH_ + sc16;
    krA = *reinterpret_cast<const uint4*>(ksrc);
    krB = *reinterpret_cast<const uint4*>(ksrc + 8);
    const unsigned short* vsrc = vb + (size_t)(kb0 + 2*kp) * DH_ + dh0;
    vrA = *reinterpret_cast<const uint4*>(vsrc);
    vrB = *reinterpret_cast<const uint4*>(vsrc + DH_);
  };
  auto WRITE = [&](int buf) {
    int sw = (sr & 7) << 4;
    int cb = sc16 * 2;
    *reinterpret_cast<uint4*>(&Ks[buf][(sr*128 + (cb ^ sw)) >> 1]) = krA;
    *reinterpret_cast<uint4*>(&Ks[buf][(sr*128 + ((cb + 16) ^ sw)) >> 1]) = krB;
    union { uint4 u4; unsigned short s[8]; } a, b;
    a.u4 = vrA; b.u4 = vrB;
#pragma unroll
    for (int j = 0; j < 8; j++) {
      int row = dh0 + j, sw2 = (row & 7) << 4;
      *reinterpret_cast<unsigned*>(&VT[buf][(row*128 + ((4*kp) ^ sw2)) >> 1]) =
          (unsigned)a.s[j] | ((unsigned)b.s[j] << 16);
    }
  };

#pragma unroll
  for (int pass = 0; pass < 2; pass++) {
    int qtile = pass ? bx : (15 - bx);   // heavy tile first
    int q0 = qtile * 128;
    int qw = q0 + wave * 32;
    int myq = qw + ql;

    short8 qf[4];
#pragma unroll
    for (int dblk = 0; dblk < 4; dblk++)
      qf[dblk] = *reinterpret_cast<const short8*>(qb + (size_t)myq * DH_ + dblk*16 + hi*8);

    f32x16 oaccT[2] = {};
    float mst = -1e30f, lst = 0.f;
    int nt = q0 / 64 + 2;

    LOADR(0);
    WRITE(0);
    __syncthreads();

    for (int kt = 0; kt < nt; kt++) {
      int kb0 = kt * 64;
      int cur = kt & 1;
      if (kt + 1 < nt) LOADR((kt + 1) * 64);   // early issue: latency hides under compute

      if (kb0 <= qw + 31) {
        // QK^T (swapped): sc[blk] col=q(lane), rows=keys
        f32x16 sc[2] = {};
#pragma unroll
        for (int dblk = 0; dblk < 4; dblk++) {
#pragma unroll
          for (int blk = 0; blk < 2; blk++) {
            int row = blk*32 + ql;
            int sw = (row & 7) << 4;
            short8 kf = *reinterpret_cast<const short8*>(
                &Ks[cur][(row*128 + (((unsigned)(dblk*32 + hi*16)) ^ sw)) >> 1]);
            sc[blk] = __builtin_amdgcn_mfma_f32_32x32x16_bf16(kf, qf[dblk], sc[blk], 0, 0, 0);
          }
        }
        bool full = (kb0 + 63 <= qw);
        if (!full) {
#pragma unroll
          for (int blk = 0; blk < 2; blk++)
#pragma unroll
            for (int r = 0; r < 16; r++) {
              int key = kb0 + blk*32 + (r & 3) + 8*(r >> 2) + 4*hi;
              if (key > myq) sc[blk][r] = -1e30f;
            }
        }
        // lane-local max
        float pm0 = -1e30f, pm1 = -1e30f, pm2 = -1e30f, pm3 = -1e30f;
#pragma unroll
        for (int blk = 0; blk < 2; blk++)
#pragma unroll
          for (int g = 0; g < 4; g++) {
            pm0 = fmaxf(pm0, sc[blk][4*g]);
            pm1 = fmaxf(pm1, sc[blk][4*g+1]);
            pm2 = fmaxf(pm2, sc[blk][4*g+2]);
            pm3 = fmaxf(pm3, sc[blk][4*g+3]);
          }
        float mx = fmaxf(fmaxf(pm0, pm1), fmaxf(pm2, pm3));
        mx = fmaxf(mx, __shfl_xor(mx, 32));
        // defer-max: rescale only when max grew past THR=8 (P bounded by 2^8)
        if (!__all(mx <= mst + 8.0f)) {
          float mnew = fmaxf(mst, mx);
          float fac = exp2f(mst - mnew);
          lst *= fac;
#pragma unroll
          for (int db = 0; db < 2; db++)
#pragma unroll
            for (int r = 0; r < 16; r++) oaccT[db][r] *= fac;
          mst = mnew;
        }
        float ps0 = 0.f, ps1 = 0.f, ps2 = 0.f, ps3 = 0.f;
#pragma unroll
        for (int blk = 0; blk < 2; blk++)
#pragma unroll
          for (int g = 0; g < 4; g++) {
            float p0 = exp2f(sc[blk][4*g]   - mst);
            float p1 = exp2f(sc[blk][4*g+1] - mst);
            float p2 = exp2f(sc[blk][4*g+2] - mst);
            float p3 = exp2f(sc[blk][4*g+3] - mst);
            ps0 += p0; ps1 += p1; ps2 += p2; ps3 += p3;
            uint2 val;
            val.x = cvt_pk_bf16(p0, p1);
            val.y = cvt_pk_bf16(p2, p3);
            int cbyte = (blk*64 + g*16 + hi*8) ^ swq;
            *reinterpret_cast<uint2*>(&Pw[(ql*128 + cbyte) >> 1]) = val;
          }
        float rs = (ps0 + ps1) + (ps2 + ps3);
        rs += __shfl_xor(rs, 32);
        lst += rs;
        // PV: O^T += mfma(A=V^T, B=P^T)
#pragma unroll
        for (int ks = 0; ks < 4; ks++) {
          int cb = ks*32 + hi*16;
          short8 pa = *reinterpret_cast<const short8*>(&Pw[(ql*128 + (cb ^ swq)) >> 1]);
#pragma unroll
          for (int db = 0; db < 2; db++) {
            int row = db*32 + ql;
            int sw = (row & 7) << 4;
            short8 vf = *reinterpret_cast<const short8*>(&VT[cur][(row*128 + (cb ^ sw)) >> 1]);
            oaccT[db] = __builtin_amdgcn_mfma_f32_32x32x16_bf16(vf, pa, oaccT[db], 0, 0, 0);
          }
        }
      }

      if (kt + 1 < nt) WRITE((kt + 1) & 1);
      __syncthreads();
    }

    // epilogue: lane owns q-column
    float inv = 1.0f / lst;
    unsigned short* ob = o + ((size_t)(bb * S_ + myq)) * D_ + hh * DH_;
#pragma unroll
    for (int db = 0; db < 2; db++)
#pragma unroll
      for (int g = 0; g < 8; g++) {
        int r = 2 * g;
        int dh = db*32 + (r & 3) + 8*(r >> 2) + 4*hi;
        unsigned pk = cvt_pk_bf16(oaccT[db][r] * inv, oaccT[db][r+1] * inv);
        *reinterpret_cast<unsigned*>(ob + dh) = pk;
      }
  }
}

extern "C" void kernel_launch(void* const* d_in, const int* in_sizes, int n_in,
                              void* d_out, int out_size, void* d_ws, size_t ws_size,
                              hipStream_t stream) {
  (void)in_sizes; (void)n_in; (void)out_size; (void)ws_size;
  const float* x    = (const float*)d_in[0];
  const float* ln1g = (const float*)d_in[1];
  const float* ln1b = (const float*)d_in[2];
  const float* Wq   = (const float*)d_in[3];
  const float* bq   = (const float*)d_in[4];
  const float* Wk   = (const float*)d_in[5];
  const float* bk   = (const float*)d_in[6];
  const float* Wv   = (const float*)d_in[7];
  const float* bv   = (const float*)d_in[8];
  const float* Wo   = (const float*)d_in[9];
  const float* bo   = (const float*)d_in[10];
  const float* ln2g = (const float*)d_in[11];
  const float* ln2b = (const float*)d_in[12];
  const float* W1   = (const float*)d_in[13];
  const float* b1   = (const float*)d_in[14];
  const float* W2   = (const float*)d_in[15];
  const float* b2   = (const float*)d_in[16];
  float* out = (float*)d_out;

  char* ws = (char*)d_ws;
  size_t off = 0;
  auto alloc = [&](size_t bytes) {
    char* p = ws + off;
    off += (bytes + 255) & ~(size_t)255;
    return p;
  };
  // NOTE: WqT/WkT/WvT contiguous => one [2304][768] B-matrix for fused QKV.
  unsigned short* WqT = (unsigned short*)alloc((size_t)D_*D_*2);
  unsigned short* WkT = (unsigned short*)alloc((size_t)D_*D_*2);
  unsigned short* WvT = (unsigned short*)alloc((size_t)D_*D_*2);
  unsigned short* WoT = (unsigned short*)alloc((size_t)D_*D_*2);
  unsigned short* W1T = (unsigned short*)alloc((size_t)D_*FF_*2);
  unsigned short* W2T = (unsigned short*)alloc((size_t)FF_*D_*2);
  unsigned short* h   = (unsigned short*)alloc((size_t)B_*S_*D_*2);
  // q/k/v contiguous => fused QKV epilogue scatters into one region.
  unsigned short* qb  = (unsigned short*)alloc((size_t)B_*S_*D_*2);
  unsigned short* kbf = (unsigned short*)alloc((size_t)B_*S_*D_*2);
  unsigned short* vbf = (unsigned short*)alloc((size_t)B_*S_*D_*2);
  unsigned short* ob  = (unsigned short*)alloc((size_t)B_*S_*D_*2);
  float* bias_cat     = (float*)alloc((size_t)3*D_*4);
  unsigned short* ffb = qb;  // reuse q/k/v region (4*B*S*D*2 >= B*S*FF*2)
  unsigned short* h2  = h;   // reuse h

  const float qscale = 0.125f * 1.4426950408889634f;  // 1/sqrt(DH) * log2(e)

  dim3 tb(32, 8);
  transpose_cast_kernel<<<dim3(D_/32,  D_/32),  tb, 0, stream>>>(Wq, WqT, D_,  D_);
  transpose_cast_kernel<<<dim3(D_/32,  D_/32),  tb, 0, stream>>>(Wk, WkT, D_,  D_);
  transpose_cast_kernel<<<dim3(D_/32,  D_/32),  tb, 0, stream>>>(Wv, WvT, D_,  D_);
  transpose_cast_kernel<<<dim3(D_/32,  D_/32),  tb, 0, stream>>>(Wo, WoT, D_,  D_);
  transpose_cast_kernel<<<dim3(D_/32,  FF_/32), tb, 0, stream>>>(W1, W1T, D_,  FF_);
  transpose_cast_kernel<<<dim3(FF_/32, D_/32),  tb, 0, stream>>>(W2, W2T, FF_, D_);
  bias_cat_kernel<<<9, 256, 0, stream>>>(bq, bk, bv, bias_cat);

  layernorm_kernel<<<(B_*S_)/4, 256, 0, stream>>>(x, ln1g, ln1b, h);

  // fused QKV: one GEMM, N = 2304
  gemm_kernel<EPI_QKV><<<dim3(3*D_/128, (B_*S_)/128), 256, 0, stream>>>(
      h, D_, WqT, D_, bias_cat, nullptr, nullptr, qb, D_, qscale);

  attn_kernel<<<dim3(384), 256, 0, stream>>>(qb, kbf, vbf, ob);

  gemm_kernel<EPI_OPROJ><<<dim3(D_/128, (B_*S_)/128), 256, 0, stream>>>(
      ob, D_, WoT, D_, bo, x, out, nullptr, D_, 1.0f);

  layernorm_kernel<<<(B_*S_)/4, 256, 0, stream>>>(out, ln2g, ln2b, h2);

  gemm_kernel<EPI_GELU><<<dim3(FF_/128, (B_*S_)/128), 256, 0, stream>>>(
      h2, D_, W1T, D_, b1, nullptr, nullptr, ffb, FF_, 1.0f);

  gemm_kernel<EPI_FINAL><<<dim3(D_/128, (B_*S_)/128), 256, 0, stream>>>(
      ffb, FF_, W2T, FF_, b2, out, out, nullptr, D_, 1.0f);
}

// Round 5
// 321.905 us; speedup vs baseline: 2.0710x; 1.1349x over previous
//
#include <hip/hip_runtime.h>
#include <math.h>

#define B_ 4
#define S_ 2048
#define D_ 768
#define H_ 12
#define DH_ 64
#define FF_ 3072

using short8  = __attribute__((ext_vector_type(8))) short;
using f32x4   = __attribute__((ext_vector_type(4))) float;
using f32x16  = __attribute__((ext_vector_type(16))) float;
using float4v = __attribute__((ext_vector_type(4))) float;
using ushort4v= __attribute__((ext_vector_type(4))) unsigned short;

__device__ __forceinline__ unsigned short f2bf(float f) {
  unsigned u = __builtin_bit_cast(unsigned, f);
  u += 0x7FFFu + ((u >> 16) & 1u);   // round-to-nearest-even
  return (unsigned short)(u >> 16);
}

__device__ __forceinline__ unsigned cvt_pk_bf16(float a, float b) {
  unsigned r;
  asm("v_cvt_pk_bf16_f32 %0, %1, %2" : "=v"(r) : "v"(a), "v"(b));
  return r;   // lo = bf16(a), hi = bf16(b)
}

__device__ __forceinline__ void gload16(const void* g, void* l) {
  __builtin_amdgcn_global_load_lds(
      (const __attribute__((address_space(1))) unsigned*)g,
      (__attribute__((address_space(3))) unsigned*)l, 16, 0, 0);
}

// ---------------- weight transpose + cast: in [K][N] f32 -> out [N][K] bf16 ----------------
__global__ __launch_bounds__(256) void transpose_cast_kernel(
    const float* __restrict__ in, unsigned short* __restrict__ out, int K, int N) {
  __shared__ float tile[32][33];
  int k0 = blockIdx.x * 32, n0 = blockIdx.y * 32;
  int tx = threadIdx.x, ty = threadIdx.y;
#pragma unroll
  for (int i = 0; i < 4; i++)
    tile[ty + 8*i][tx] = in[(size_t)(k0 + ty + 8*i) * N + n0 + tx];
  __syncthreads();
#pragma unroll
  for (int i = 0; i < 4; i++)
    out[(size_t)(n0 + ty + 8*i) * K + k0 + tx] = f2bf(tile[tx][ty + 8*i]);
}

// ---------------- bias concat: [bq | bk | bv] -> 2304 floats ----------------
__global__ void bias_cat_kernel(const float* __restrict__ bq, const float* __restrict__ bk,
                                const float* __restrict__ bv, float* __restrict__ dst) {
  int i = blockIdx.x * 256 + threadIdx.x;
  if (i >= 3 * D_) return;
  float v;
  if (i < D_)            v = bq[i];
  else if (i < 2 * D_)   v = bk[i - D_];
  else                   v = bv[i - 2 * D_];
  dst[i] = v;
}

// ---------------- LayerNorm: fp32 in -> bf16 out, one wave per row of 768 ----------------
__global__ __launch_bounds__(256) void layernorm_kernel(
    const float* __restrict__ x, const float* __restrict__ g,
    const float* __restrict__ b, unsigned short* __restrict__ out) {
  int wave = threadIdx.x >> 6, lane = threadIdx.x & 63;
  int row = blockIdx.x * 4 + wave;
  const float* xr = x + (size_t)row * D_;
  float4v v[3];
  float sum = 0.f, sq = 0.f;
#pragma unroll
  for (int i = 0; i < 3; i++) {
    v[i] = reinterpret_cast<const float4v*>(xr)[lane + 64*i];
#pragma unroll
    for (int j = 0; j < 4; j++) { sum += v[i][j]; sq += v[i][j]*v[i][j]; }
  }
#pragma unroll
  for (int d = 1; d < 64; d <<= 1) { sum += __shfl_xor(sum, d); sq += __shfl_xor(sq, d); }
  float mu   = sum * (1.0f / D_);
  float var  = sq  * (1.0f / D_) - mu * mu;
  float rstd = rsqrtf(var + 1e-5f);
  unsigned short* orow = out + (size_t)row * D_;
#pragma unroll
  for (int i = 0; i < 3; i++) {
    int idx = (lane + 64*i) * 4;
    ushort4v o;
#pragma unroll
    for (int j = 0; j < 4; j++)
      o[j] = f2bf((v[i][j] - mu) * rstd * g[idx + j] + b[idx + j]);
    *reinterpret_cast<ushort4v*>(orow + idx) = o;
  }
}

// ---------------- bf16 MFMA GEMM v2 ----------------
// 128x128 tile, BK=32, 4 waves, double-buffered LDS (32 KB) with T3-min overlap:
// issue next-tile global_load_lds BEFORE compute, one __syncthreads per K-step.
// LDS source-side XOR swizzle (slot^(row&3)) kills the 16-way ds_read conflict.
// XCD M-clustering: bid&7 selects the XCD's M-panel group (A L2 reuse).
#define EPI_QKV   0
#define EPI_OPROJ 1
#define EPI_GELU  2
#define EPI_FINAL 3

template<int EPI>
__global__ __launch_bounds__(256) void gemm_kernel(
    const unsigned short* __restrict__ A, int lda,
    const unsigned short* __restrict__ BT, int K,
    const float* __restrict__ bias,
    const float* __restrict__ resid,
    float* __restrict__ outf,
    unsigned short* __restrict__ outh,
    int ldo, float ascale, int nN) {
  __shared__ __attribute__((aligned(16))) unsigned short As[2][128*32];
  __shared__ __attribute__((aligned(16))) unsigned short Bs[2][128*32];
  int tid = threadIdx.x;
  int wave = tid >> 6, lane = tid & 63;
  int lrow = lane & 15, lk = lane >> 4;      // lk = 16B slot 0..3
  // XCD-clustered block mapping: nM = 64 panels, 8 per XCD; n iterates fastest.
  int bid = blockIdx.x;
  int xcd = bid & 7, j = bid >> 3;
  int nM8 = gridDim.x / (8 * nN);            // = nM/8 = 8
  int m0 = (xcd * nM8 + j / nN) * 128;
  int n0 = (j % nN) * 128;
  int wm = (wave >> 1) * 64, wn = (wave & 1) * 64;

  auto STAGE = [&](int buf, int k0) {
#pragma unroll
    for (int i = 0; i < 2; i++) {
      int ch = i * 256 + tid;
      int row = ch >> 2, slot = ch & 3;
      int col = k0 + 8 * (slot ^ (row & 3));   // pre-swizzled source
      gload16(A  + (size_t)(m0 + row) * lda + col, &As[buf][(i*256 + wave*64) * 8]);
      gload16(BT + (size_t)(n0 + row) * K   + col, &Bs[buf][(i*256 + wave*64) * 8]);
    }
  };

  f32x4 acc[4][4] = {};
  STAGE(0, 0);
  __syncthreads();
  int nt = K / 32;
  for (int t = 0; t < nt; t++) {
    int cur = t & 1;
    if (t + 1 < nt) STAGE(cur ^ 1, (t + 1) * 32);   // issue early: hides under compute
    short8 af[4], bf[4];
#pragma unroll
    for (int mi = 0; mi < 4; mi++) {
      int row = wm + mi*16 + lrow;
      af[mi] = *reinterpret_cast<const short8*>(&As[cur][row*32 + ((lk ^ (row & 3)) * 8)]);
    }
#pragma unroll
    for (int ni = 0; ni < 4; ni++) {
      int row = wn + ni*16 + lrow;
      bf[ni] = *reinterpret_cast<const short8*>(&Bs[cur][row*32 + ((lk ^ (row & 3)) * 8)]);
    }
#pragma unroll
    for (int mi = 0; mi < 4; mi++)
#pragma unroll
      for (int ni = 0; ni < 4; ni++)
        acc[mi][ni] = __builtin_amdgcn_mfma_f32_16x16x32_bf16(af[mi], bf[ni], acc[mi][ni], 0, 0, 0);
    __syncthreads();   // drains vmcnt (next tile staged) + protects dbuf swap
  }
  int pproj = (EPI == EPI_QKV) ? (n0 / D_) : 0;  // uniform per block (128 | 768)
#pragma unroll
  for (int mi = 0; mi < 4; mi++) {
#pragma unroll
    for (int ni = 0; ni < 4; ni++) {
#pragma unroll
      for (int r = 0; r < 4; r++) {
        int gm = m0 + wm + mi*16 + (lane >> 4)*4 + r;
        int gn = n0 + wn + ni*16 + lrow;
        float v = acc[mi][ni][r] + bias[gn];
        if constexpr (EPI == EPI_QKV) {
          if (gn < D_) v *= ascale;   // Q pre-scale: 1/sqrt(DH)*log2(e)
          int c = gn - pproj * D_;
          size_t idx = (((size_t)(pproj*B_ + (gm >> 11)) * H_ + (c >> 6)) * S_ + (gm & 2047)) * DH_ + (c & 63);
          outh[idx] = f2bf(v);
        } else if constexpr (EPI == EPI_OPROJ) {
          size_t idx = (size_t)gm * ldo + gn;
          outf[idx] = v + resid[idx];
        } else if constexpr (EPI == EPI_GELU) {
          float gv = 0.5f * v * (1.0f + erff(v * 0.70710678118654752f));
          outh[(size_t)gm * ldo + gn] = f2bf(gv);
        } else {  // EPI_FINAL
          size_t idx = (size_t)gm * ldo + gn;
          outf[idx] = v + resid[idx];
        }
      }
    }
  }
}

// ---------------- causal flash attention v4 ----------------
// Fold-paired uniform blocks (q-tiles bx & 15-bx), XCD-aware bh mapping,
// double-buffered K/V with early-issue reg staging, swapped-operand 32x32x16,
// lane-local softmax + defer-max (THR=8 in log2 domain), cvt_pk bf16 packing.
__global__ __launch_bounds__(256) void attn_kernel(
    const unsigned short* __restrict__ q,
    const unsigned short* __restrict__ k,
    const unsigned short* __restrict__ v,
    unsigned short* __restrict__ o) {
  __shared__ __attribute__((aligned(16))) unsigned short Ks[2][64*64];  // [key][dh] swizzled
  __shared__ __attribute__((aligned(16))) unsigned short VT[2][64*64];  // [dh][key] swizzled
  __shared__ __attribute__((aligned(16))) unsigned short P2[4][32*64];  // per-wave [q][key] swizzled
  int tid = threadIdx.x;
  int wave = tid >> 6, lane = tid & 63;
  int ql = lane & 31, hi = lane >> 5;
  // 384 blocks: xcd = bid%8 hosts 6 bh; all 8 fold-blocks of a bh on one XCD.
  int bid = blockIdx.x;
  int xcd = bid & 7, kk = bid >> 3;
  int bx = kk & 7;                 // fold index 0..7 -> q-tiles {15-bx, bx}
  int bh = (kk >> 3) * 8 + xcd;    // 0..47
  const unsigned short* qb = q + (size_t)bh * S_ * DH_;
  const unsigned short* kb = k + (size_t)bh * S_ * DH_;
  const unsigned short* vb = v + (size_t)bh * S_ * DH_;
  unsigned short* Pw = P2[wave];
  int swq = (ql & 7) << 4;
  int bb = bh / H_, hh = bh % H_;

  // staging geometry
  int sr = tid >> 2;                 // K row 0..63
  int sc16 = (tid & 3) * 16;         // K col (elems)
  int kp = tid & 31, dh0 = (tid >> 5) * 8;
  uint4 krA, krB, vrA, vrB;

  auto LOADR = [&](int kb0) {
    const unsigned short* ksrc = kb + (size_t)(kb0 + sr) * DH_ + sc16;
    krA = *reinterpret_cast<const uint4*>(ksrc);
    krB = *reinterpret_cast<const uint4*>(ksrc + 8);
    const unsigned short* vsrc = vb + (size_t)(kb0 + 2*kp) * DH_ + dh0;
    vrA = *reinterpret_cast<const uint4*>(vsrc);
    vrB = *reinterpret_cast<const uint4*>(vsrc + DH_);
  };
  auto WRITE = [&](int buf) {
    int sw = (sr & 7) << 4;
    int cb = sc16 * 2;
    *reinterpret_cast<uint4*>(&Ks[buf][(sr*128 + (cb ^ sw)) >> 1]) = krA;
    *reinterpret_cast<uint4*>(&Ks[buf][(sr*128 + ((cb + 16) ^ sw)) >> 1]) = krB;
    union { uint4 u4; unsigned short s[8]; } a, b;
    a.u4 = vrA; b.u4 = vrB;
#pragma unroll
    for (int j = 0; j < 8; j++) {
      int row = dh0 + j, sw2 = (row & 7) << 4;
      *reinterpret_cast<unsigned*>(&VT[buf][(row*128 + ((4*kp) ^ sw2)) >> 1]) =
          (unsigned)a.s[j] | ((unsigned)b.s[j] << 16);
    }
  };

#pragma unroll
  for (int pass = 0; pass < 2; pass++) {
    int qtile = pass ? bx : (15 - bx);   // heavy tile first
    int q0 = qtile * 128;
    int qw = q0 + wave * 32;
    int myq = qw + ql;

    short8 qf[4];
#pragma unroll
    for (int dblk = 0; dblk < 4; dblk++)
      qf[dblk] = *reinterpret_cast<const short8*>(qb + (size_t)myq * DH_ + dblk*16 + hi*8);

    f32x16 oaccT[2] = {};
    float mst = -1e30f, lst = 0.f;
    int nt = q0 / 64 + 2;

    LOADR(0);
    WRITE(0);
    __syncthreads();

    for (int kt = 0; kt < nt; kt++) {
      int kb0 = kt * 64;
      int cur = kt & 1;
      if (kt + 1 < nt) LOADR((kt + 1) * 64);   // early issue: latency hides under compute

      if (kb0 <= qw + 31) {
        // QK^T (swapped): sc[blk] col=q(lane), rows=keys
        f32x16 sc[2] = {};
#pragma unroll
        for (int dblk = 0; dblk < 4; dblk++) {
#pragma unroll
          for (int blk = 0; blk < 2; blk++) {
            int row = blk*32 + ql;
            int sw = (row & 7) << 4;
            short8 kf = *reinterpret_cast<const short8*>(
                &Ks[cur][(row*128 + (((unsigned)(dblk*32 + hi*16)) ^ sw)) >> 1]);
            sc[blk] = __builtin_amdgcn_mfma_f32_32x32x16_bf16(kf, qf[dblk], sc[blk], 0, 0, 0);
          }
        }
        bool full = (kb0 + 63 <= qw);
        if (!full) {
#pragma unroll
          for (int blk = 0; blk < 2; blk++)
#pragma unroll
            for (int r = 0; r < 16; r++) {
              int key = kb0 + blk*32 + (r & 3) + 8*(r >> 2) + 4*hi;
              if (key > myq) sc[blk][r] = -1e30f;
            }
        }
        // lane-local max
        float pm0 = -1e30f, pm1 = -1e30f, pm2 = -1e30f, pm3 = -1e30f;
#pragma unroll
        for (int blk = 0; blk < 2; blk++)
#pragma unroll
          for (int g = 0; g < 4; g++) {
            pm0 = fmaxf(pm0, sc[blk][4*g]);
            pm1 = fmaxf(pm1, sc[blk][4*g+1]);
            pm2 = fmaxf(pm2, sc[blk][4*g+2]);
            pm3 = fmaxf(pm3, sc[blk][4*g+3]);
          }
        float mx = fmaxf(fmaxf(pm0, pm1), fmaxf(pm2, pm3));
        mx = fmaxf(mx, __shfl_xor(mx, 32));
        // defer-max: rescale only when max grew past THR=8 (P bounded by 2^8)
        if (!__all(mx <= mst + 8.0f)) {
          float mnew = fmaxf(mst, mx);
          float fac = exp2f(mst - mnew);
          lst *= fac;
#pragma unroll
          for (int db = 0; db < 2; db++)
#pragma unroll
            for (int r = 0; r < 16; r++) oaccT[db][r] *= fac;
          mst = mnew;
        }
        float ps0 = 0.f, ps1 = 0.f, ps2 = 0.f, ps3 = 0.f;
#pragma unroll
        for (int blk = 0; blk < 2; blk++)
#pragma unroll
          for (int g = 0; g < 4; g++) {
            float p0 = exp2f(sc[blk][4*g]   - mst);
            float p1 = exp2f(sc[blk][4*g+1] - mst);
            float p2 = exp2f(sc[blk][4*g+2] - mst);
            float p3 = exp2f(sc[blk][4*g+3] - mst);
            ps0 += p0; ps1 += p1; ps2 += p2; ps3 += p3;
            uint2 val;
            val.x = cvt_pk_bf16(p0, p1);
            val.y = cvt_pk_bf16(p2, p3);
            int cbyte = (blk*64 + g*16 + hi*8) ^ swq;
            *reinterpret_cast<uint2*>(&Pw[(ql*128 + cbyte) >> 1]) = val;
          }
        float rs = (ps0 + ps1) + (ps2 + ps3);
        rs += __shfl_xor(rs, 32);
        lst += rs;
        // PV: O^T += mfma(A=V^T, B=P^T)
#pragma unroll
        for (int ks = 0; ks < 4; ks++) {
          int cb = ks*32 + hi*16;
          short8 pa = *reinterpret_cast<const short8*>(&Pw[(ql*128 + (cb ^ swq)) >> 1]);
#pragma unroll
          for (int db = 0; db < 2; db++) {
            int row = db*32 + ql;
            int sw = (row & 7) << 4;
            short8 vf = *reinterpret_cast<const short8*>(&VT[cur][(row*128 + (cb ^ sw)) >> 1]);
            oaccT[db] = __builtin_amdgcn_mfma_f32_32x32x16_bf16(vf, pa, oaccT[db], 0, 0, 0);
          }
        }
      }

      if (kt + 1 < nt) WRITE((kt + 1) & 1);
      __syncthreads();
    }

    // epilogue: lane owns q-column
    float inv = 1.0f / lst;
    unsigned short* ob = o + ((size_t)(bb * S_ + myq)) * D_ + hh * DH_;
#pragma unroll
    for (int db = 0; db < 2; db++)
#pragma unroll
      for (int g = 0; g < 8; g++) {
        int r = 2 * g;
        int dh = db*32 + (r & 3) + 8*(r >> 2) + 4*hi;
        unsigned pk = cvt_pk_bf16(oaccT[db][r] * inv, oaccT[db][r+1] * inv);
        *reinterpret_cast<unsigned*>(ob + dh) = pk;
      }
  }
}

extern "C" void kernel_launch(void* const* d_in, const int* in_sizes, int n_in,
                              void* d_out, int out_size, void* d_ws, size_t ws_size,
                              hipStream_t stream) {
  (void)in_sizes; (void)n_in; (void)out_size; (void)ws_size;
  const float* x    = (const float*)d_in[0];
  const float* ln1g = (const float*)d_in[1];
  const float* ln1b = (const float*)d_in[2];
  const float* Wq   = (const float*)d_in[3];
  const float* bq   = (const float*)d_in[4];
  const float* Wk   = (const float*)d_in[5];
  const float* bk   = (const float*)d_in[6];
  const float* Wv   = (const float*)d_in[7];
  const float* bv   = (const float*)d_in[8];
  const float* Wo   = (const float*)d_in[9];
  const float* bo   = (const float*)d_in[10];
  const float* ln2g = (const float*)d_in[11];
  const float* ln2b = (const float*)d_in[12];
  const float* W1   = (const float*)d_in[13];
  const float* b1   = (const float*)d_in[14];
  const float* W2   = (const float*)d_in[15];
  const float* b2   = (const float*)d_in[16];
  float* out = (float*)d_out;

  char* ws = (char*)d_ws;
  size_t off = 0;
  auto alloc = [&](size_t bytes) {
    char* p = ws + off;
    off += (bytes + 255) & ~(size_t)255;
    return p;
  };
  // NOTE: WqT/WkT/WvT contiguous => one [2304][768] B-matrix for fused QKV.
  unsigned short* WqT = (unsigned short*)alloc((size_t)D_*D_*2);
  unsigned short* WkT = (unsigned short*)alloc((size_t)D_*D_*2);
  unsigned short* WvT = (unsigned short*)alloc((size_t)D_*D_*2);
  unsigned short* WoT = (unsigned short*)alloc((size_t)D_*D_*2);
  unsigned short* W1T = (unsigned short*)alloc((size_t)D_*FF_*2);
  unsigned short* W2T = (unsigned short*)alloc((size_t)FF_*D_*2);
  unsigned short* h   = (unsigned short*)alloc((size_t)B_*S_*D_*2);
  // q/k/v contiguous => fused QKV epilogue scatters into one region.
  unsigned short* qb  = (unsigned short*)alloc((size_t)B_*S_*D_*2);
  unsigned short* kbf = (unsigned short*)alloc((size_t)B_*S_*D_*2);
  unsigned short* vbf = (unsigned short*)alloc((size_t)B_*S_*D_*2);
  unsigned short* ob  = (unsigned short*)alloc((size_t)B_*S_*D_*2);
  float* bias_cat     = (float*)alloc((size_t)3*D_*4);
  unsigned short* ffb = qb;  // reuse q/k/v region (4*B*S*D*2 >= B*S*FF*2)
  unsigned short* h2  = h;   // reuse h

  const float qscale = 0.125f * 1.4426950408889634f;  // 1/sqrt(DH) * log2(e)

  dim3 tb(32, 8);
  transpose_cast_kernel<<<dim3(D_/32,  D_/32),  tb, 0, stream>>>(Wq, WqT, D_,  D_);
  transpose_cast_kernel<<<dim3(D_/32,  D_/32),  tb, 0, stream>>>(Wk, WkT, D_,  D_);
  transpose_cast_kernel<<<dim3(D_/32,  D_/32),  tb, 0, stream>>>(Wv, WvT, D_,  D_);
  transpose_cast_kernel<<<dim3(D_/32,  D_/32),  tb, 0, stream>>>(Wo, WoT, D_,  D_);
  transpose_cast_kernel<<<dim3(D_/32,  FF_/32), tb, 0, stream>>>(W1, W1T, D_,  FF_);
  transpose_cast_kernel<<<dim3(FF_/32, D_/32),  tb, 0, stream>>>(W2, W2T, FF_, D_);
  bias_cat_kernel<<<9, 256, 0, stream>>>(bq, bk, bv, bias_cat);

  layernorm_kernel<<<(B_*S_)/4, 256, 0, stream>>>(x, ln1g, ln1b, h);

  // fused QKV: one GEMM, N = 2304 (nN = 18)
  gemm_kernel<EPI_QKV><<<dim3(64*18), 256, 0, stream>>>(
      h, D_, WqT, D_, bias_cat, nullptr, nullptr, qb, D_, qscale, 18);

  attn_kernel<<<dim3(384), 256, 0, stream>>>(qb, kbf, vbf, ob);

  gemm_kernel<EPI_OPROJ><<<dim3(64*6), 256, 0, stream>>>(
      ob, D_, WoT, D_, bo, x, out, nullptr, D_, 1.0f, 6);

  layernorm_kernel<<<(B_*S_)/4, 256, 0, stream>>>(out, ln2g, ln2b, h2);

  gemm_kernel<EPI_GELU><<<dim3(64*24), 256, 0, stream>>>(
      h2, D_, W1T, D_, b1, nullptr, nullptr, ffb, FF_, 1.0f, 24);

  gemm_kernel<EPI_FINAL><<<dim3(64*6), 256, 0, stream>>>(
      ffb, FF_, W2T, FF_, b2, out, out, nullptr, D_, 1.0f, 6);
}

// Round 6
// 278.337 us; speedup vs baseline: 2.3952x; 1.1565x over previous
//
#include <hip/hip_runtime.h>
#include <math.h>

#define B_ 4
#define S_ 2048
#define D_ 768
#define H_ 12
#define DH_ 64
#define FF_ 3072
#define LDQ (3*D_)

using short8  = __attribute__((ext_vector_type(8))) short;
using f32x4   = __attribute__((ext_vector_type(4))) float;
using f32x16  = __attribute__((ext_vector_type(16))) float;
using float4v = __attribute__((ext_vector_type(4))) float;
using ushort4v= __attribute__((ext_vector_type(4))) unsigned short;

__device__ __forceinline__ unsigned short f2bf(float f) {
  unsigned u = __builtin_bit_cast(unsigned, f);
  u += 0x7FFFu + ((u >> 16) & 1u);   // round-to-nearest-even
  return (unsigned short)(u >> 16);
}

__device__ __forceinline__ unsigned cvt_pk_bf16(float a, float b) {
  unsigned r;
  asm("v_cvt_pk_bf16_f32 %0, %1, %2" : "=v"(r) : "v"(a), "v"(b));
  return r;   // lo = bf16(a), hi = bf16(b)
}

__device__ __forceinline__ void gload16(const void* g, void* l) {
  __builtin_amdgcn_global_load_lds(
      (const __attribute__((address_space(1))) unsigned*)g,
      (__attribute__((address_space(3))) unsigned*)l, 16, 0, 0);
}

// ---------------- fused weight transpose + cast (all 6 weights, one launch) ----------------
// in [K][N] f32 -> out [N][K] bf16
__global__ __launch_bounds__(256) void transpose_cast_multi_kernel(
    const float* __restrict__ Wq, const float* __restrict__ Wk,
    const float* __restrict__ Wv, const float* __restrict__ Wo,
    const float* __restrict__ W1, const float* __restrict__ W2,
    unsigned short* __restrict__ WqT, unsigned short* __restrict__ WkT,
    unsigned short* __restrict__ WvT, unsigned short* __restrict__ WoT,
    unsigned short* __restrict__ W1T, unsigned short* __restrict__ W2T) {
  __shared__ float tile[32][33];
  int bid = blockIdx.x;
  const float* in; unsigned short* out; int K, N, t;
  if (bid < 2304) {                 // Wq/Wk/Wv/Wo: 576 tiles each, 768x768
    int seg = bid / 576; t = bid % 576; K = D_; N = D_;
    in  = seg == 0 ? Wq  : seg == 1 ? Wk  : seg == 2 ? Wv  : Wo;
    out = seg == 0 ? WqT : seg == 1 ? WkT : seg == 2 ? WvT : WoT;
  } else if (bid < 4608) {          // W1: 768x3072
    t = bid - 2304; K = D_; N = FF_; in = W1; out = W1T;
  } else {                          // W2: 3072x768
    t = bid - 4608; K = FF_; N = D_; in = W2; out = W2T;
  }
  int ntk = K / 32;
  int k0 = (t % ntk) * 32, n0 = (t / ntk) * 32;
  int tx = threadIdx.x, ty = threadIdx.y;
#pragma unroll
  for (int i = 0; i < 4; i++)
    tile[ty + 8*i][tx] = in[(size_t)(k0 + ty + 8*i) * N + n0 + tx];
  __syncthreads();
#pragma unroll
  for (int i = 0; i < 4; i++)
    out[(size_t)(n0 + ty + 8*i) * K + k0 + tx] = f2bf(tile[tx][ty + 8*i]);
}

// ---------------- bias concat: [bq | bk | bv] -> 2304 floats ----------------
__global__ void bias_cat_kernel(const float* __restrict__ bq, const float* __restrict__ bk,
                                const float* __restrict__ bv, float* __restrict__ dst) {
  int i = blockIdx.x * 256 + threadIdx.x;
  if (i >= 3 * D_) return;
  float v;
  if (i < D_)            v = bq[i];
  else if (i < 2 * D_)   v = bk[i - D_];
  else                   v = bv[i - 2 * D_];
  dst[i] = v;
}

// ---------------- LayerNorm: fp32 in -> bf16 out, one wave per row of 768 ----------------
__global__ __launch_bounds__(256) void layernorm_kernel(
    const float* __restrict__ x, const float* __restrict__ g,
    const float* __restrict__ b, unsigned short* __restrict__ out) {
  int wave = threadIdx.x >> 6, lane = threadIdx.x & 63;
  int row = blockIdx.x * 4 + wave;
  const float* xr = x + (size_t)row * D_;
  float4v v[3];
  float sum = 0.f, sq = 0.f;
#pragma unroll
  for (int i = 0; i < 3; i++) {
    v[i] = reinterpret_cast<const float4v*>(xr)[lane + 64*i];
#pragma unroll
    for (int j = 0; j < 4; j++) { sum += v[i][j]; sq += v[i][j]*v[i][j]; }
  }
#pragma unroll
  for (int d = 1; d < 64; d <<= 1) { sum += __shfl_xor(sum, d); sq += __shfl_xor(sq, d); }
  float mu   = sum * (1.0f / D_);
  float var  = sq  * (1.0f / D_) - mu * mu;
  float rstd = rsqrtf(var + 1e-5f);
  unsigned short* orow = out + (size_t)row * D_;
#pragma unroll
  for (int i = 0; i < 3; i++) {
    int idx = (lane + 64*i) * 4;
    ushort4v o;
#pragma unroll
    for (int j = 0; j < 4; j++)
      o[j] = f2bf((v[i][j] - mu) * rstd * g[idx + j] + b[idx + j]);
    *reinterpret_cast<ushort4v*>(orow + idx) = o;
  }
}

// ---------------- bf16 MFMA GEMM v3 ----------------
// 128x128 tile, BK=32, 4 waves. Unified A|B LDS row (128B, 8x16B slots, ^(row&7)
// swizzle -> 2-way = free). 3-buffer pipeline with counted vmcnt(4) + raw
// s_barrier: loads for t+1,t+2 stay in flight across barriers (never drain to 0).
// XCD M-clustering: bid&7 selects the XCD's M-panel group (A L2 reuse).
#define EPI_QKV   0
#define EPI_OPROJ 1
#define EPI_GELU  2
#define EPI_FINAL 3

template<int EPI>
__global__ __launch_bounds__(256) void gemm_kernel(
    const unsigned short* __restrict__ A, int lda,
    const unsigned short* __restrict__ BT, int K,
    const float* __restrict__ bias,
    const float* __restrict__ resid,
    float* __restrict__ outf,
    unsigned short* __restrict__ outh,
    int ldo, float ascale, int nN) {
  __shared__ __attribute__((aligned(16))) unsigned short Ls[3][128*64];
  int tid = threadIdx.x;
  int wave = tid >> 6, lane = tid & 63;
  int lrow = lane & 15, lk = lane >> 4;      // lk = k-slot 0..3 (8 elems each)
  int bid = blockIdx.x;
  int xcd = bid & 7, j = bid >> 3;
  int nM8 = gridDim.x / (8 * nN);            // = 8 (64 M-panels / 8 XCDs)
  int m0 = (xcd * nM8 + j / nN) * 128;
  int n0 = (j % nN) * 128;
  int wm = (wave >> 1) * 64, wn = (wave & 1) * 64;

  // Unified staging: LDS row r = [A[m0+r] slots 0..3 | B[n0+r] slots 4..7],
  // slot s8 holds content m = s8 ^ (r&7). Source pre-swizzled per-lane (rule #21).
  auto STAGE = [&](int buf, int k0) {
#pragma unroll
    for (int i = 0; i < 4; i++) {
      int ch = i * 256 + tid;
      int row = ch >> 3, s8 = ch & 7;
      int m = s8 ^ (row & 7);
      const unsigned short* src = (m < 4)
        ? A  + (size_t)(m0 + row) * lda + k0 + m * 8
        : BT + (size_t)(n0 + row) * K   + k0 + (m - 4) * 8;
      gload16(src, &Ls[buf][(i*256 + wave*64) * 8]);
    }
  };

  f32x4 acc[4][4] = {};
  int nt = K / 32;
  STAGE(0, 0);
  STAGE(1, 32);
  for (int t = 0; t < nt; t++) {
    // counted wait: stages t+1 (and t+2 after issue) stay in flight
    if (t + 1 < nt) { asm volatile("s_waitcnt vmcnt(4)" ::: "memory"); }
    else            { asm volatile("s_waitcnt vmcnt(0)" ::: "memory"); }
    __builtin_amdgcn_s_barrier();
    const unsigned short* Lc = Ls[t % 3];
    short8 af[4], bf[4];
#pragma unroll
    for (int mi = 0; mi < 4; mi++) {
      int row = wm + mi*16 + lrow;
      af[mi] = *reinterpret_cast<const short8*>(&Lc[row*64 + ((lk ^ (row & 7)) * 8)]);
    }
#pragma unroll
    for (int ni = 0; ni < 4; ni++) {
      int row = wn + ni*16 + lrow;
      bf[ni] = *reinterpret_cast<const short8*>(&Lc[row*64 + (((4 + lk) ^ (row & 7)) * 8)]);
    }
    if (t + 2 < nt) STAGE((t + 2) % 3, (t + 2) * 32);
    __builtin_amdgcn_s_setprio(1);
#pragma unroll
    for (int mi = 0; mi < 4; mi++)
#pragma unroll
      for (int ni = 0; ni < 4; ni++)
        acc[mi][ni] = __builtin_amdgcn_mfma_f32_16x16x32_bf16(af[mi], bf[ni], acc[mi][ni], 0, 0, 0);
    __builtin_amdgcn_s_setprio(0);
  }
#pragma unroll
  for (int mi = 0; mi < 4; mi++) {
#pragma unroll
    for (int ni = 0; ni < 4; ni++) {
#pragma unroll
      for (int r = 0; r < 4; r++) {
        int gm = m0 + wm + mi*16 + (lane >> 4)*4 + r;
        int gn = n0 + wn + ni*16 + lrow;
        float v = acc[mi][ni][r] + bias[gn];
        if constexpr (EPI == EPI_QKV) {
          if (gn < D_) v *= ascale;   // Q pre-scale: 1/sqrt(DH)*log2(e)
          outh[(size_t)gm * ldo + gn] = f2bf(v);   // linear [8192][2304]
        } else if constexpr (EPI == EPI_OPROJ) {
          size_t idx = (size_t)gm * ldo + gn;
          outf[idx] = v + resid[idx];
        } else if constexpr (EPI == EPI_GELU) {
          float gv = 0.5f * v * (1.0f + erff(v * 0.70710678118654752f));
          outh[(size_t)gm * ldo + gn] = f2bf(gv);
        } else {  // EPI_FINAL
          size_t idx = (size_t)gm * ldo + gn;
          outf[idx] = v + resid[idx];
        }
      }
    }
  }
}

// ---------------- causal flash attention v5 ----------------
// 768 one-q-tile blocks (3 blocks/CU resident, 12 waves/CU), heavy tiles first,
// per-bh XCD clustering (6 bh/XCD -> K/V L2-resident). Reads strided qkv
// [8192][2304] (no scatter). Swapped-operand 32x32x16, lane-local softmax,
// defer-max, cvt_pk packing, double-buffered K/V reg-staging, setprio on MFMA.
__global__ __launch_bounds__(256) void attn_kernel(
    const unsigned short* __restrict__ qkv,
    unsigned short* __restrict__ o) {
  __shared__ __attribute__((aligned(16))) unsigned short Ks[2][64*64];  // [key][dh] swizzled
  __shared__ __attribute__((aligned(16))) unsigned short VT[2][64*64];  // [dh][key] swizzled
  __shared__ __attribute__((aligned(16))) unsigned short P2[4][32*64];  // per-wave [q][key] swizzled
  int tid = threadIdx.x;
  int wave = tid >> 6, lane = tid & 63;
  int ql = lane & 31, hi = lane >> 5;
  // 768 blocks: xcd=bid&7 hosts 6 bh; r ascending -> qtile descending (heavy first)
  int bid = blockIdx.x;
  int xcd = bid & 7, r = bid >> 3;           // r in [0,96)
  int bh = xcd * 6 + (r % 6);                // 0..47, fixed per XCD
  int qtile = 15 - (r / 6);                  // heavy (15) first
  int bb = bh / H_, hh = bh % H_;
  const unsigned short* qb = qkv + (size_t)bb * S_ * LDQ + hh * DH_;
  const unsigned short* kb = qb + D_;
  const unsigned short* vb = qb + 2 * D_;
  unsigned short* Pw = P2[wave];
  int swq = (ql & 7) << 4;

  // staging geometry
  int sr = tid >> 2;                 // K row 0..63
  int sc16 = (tid & 3) * 16;         // K col (elems)
  int kp = tid & 31, dh0 = (tid >> 5) * 8;
  uint4 krA, krB, vrA, vrB;

  auto LOADR = [&](int kb0) {
    const unsigned short* ksrc = kb + (size_t)(kb0 + sr) * LDQ + sc16;
    krA = *reinterpret_cast<const uint4*>(ksrc);
    krB = *reinterpret_cast<const uint4*>(ksrc + 8);
    const unsigned short* vsrc = vb + (size_t)(kb0 + 2*kp) * LDQ + dh0;
    vrA = *reinterpret_cast<const uint4*>(vsrc);
    vrB = *reinterpret_cast<const uint4*>(vsrc + LDQ);
  };
  auto WRITE = [&](int buf) {
    int sw = (sr & 7) << 4;
    int cb = sc16 * 2;
    *reinterpret_cast<uint4*>(&Ks[buf][(sr*128 + (cb ^ sw)) >> 1]) = krA;
    *reinterpret_cast<uint4*>(&Ks[buf][(sr*128 + ((cb + 16) ^ sw)) >> 1]) = krB;
    union { uint4 u4; unsigned short s[8]; } a, b;
    a.u4 = vrA; b.u4 = vrB;
#pragma unroll
    for (int j2 = 0; j2 < 8; j2++) {
      int row = dh0 + j2, sw2 = (row & 7) << 4;
      *reinterpret_cast<unsigned*>(&VT[buf][(row*128 + ((4*kp) ^ sw2)) >> 1]) =
          (unsigned)a.s[j2] | ((unsigned)b.s[j2] << 16);
    }
  };

  int q0 = qtile * 128;
  int qw = q0 + wave * 32;
  int myq = qw + ql;

  short8 qf[4];
#pragma unroll
  for (int dblk = 0; dblk < 4; dblk++)
    qf[dblk] = *reinterpret_cast<const short8*>(qb + (size_t)myq * LDQ + dblk*16 + hi*8);

  f32x16 oaccT[2] = {};
  float mst = -1e30f, lst = 0.f;
  int nt = q0 / 64 + 2;

  LOADR(0);
  WRITE(0);
  __syncthreads();

  for (int kt = 0; kt < nt; kt++) {
    int kb0 = kt * 64;
    int cur = kt & 1;
    if (kt + 1 < nt) LOADR((kt + 1) * 64);   // early issue: latency hides under compute

    if (kb0 <= qw + 31) {
      // QK^T (swapped): sc[blk] col=q(lane), rows=keys
      f32x16 sc[2] = {};
      __builtin_amdgcn_s_setprio(1);
#pragma unroll
      for (int dblk = 0; dblk < 4; dblk++) {
#pragma unroll
        for (int blk = 0; blk < 2; blk++) {
          int row = blk*32 + ql;
          int sw = (row & 7) << 4;
          short8 kf = *reinterpret_cast<const short8*>(
              &Ks[cur][(row*128 + (((unsigned)(dblk*32 + hi*16)) ^ sw)) >> 1]);
          sc[blk] = __builtin_amdgcn_mfma_f32_32x32x16_bf16(kf, qf[dblk], sc[blk], 0, 0, 0);
        }
      }
      __builtin_amdgcn_s_setprio(0);
      bool full = (kb0 + 63 <= qw);
      if (!full) {
#pragma unroll
        for (int blk = 0; blk < 2; blk++)
#pragma unroll
          for (int r2 = 0; r2 < 16; r2++) {
            int key = kb0 + blk*32 + (r2 & 3) + 8*(r2 >> 2) + 4*hi;
            if (key > myq) sc[blk][r2] = -1e30f;
          }
      }
      // lane-local max
      float pm0 = -1e30f, pm1 = -1e30f, pm2 = -1e30f, pm3 = -1e30f;
#pragma unroll
      for (int blk = 0; blk < 2; blk++)
#pragma unroll
        for (int g = 0; g < 4; g++) {
          pm0 = fmaxf(pm0, sc[blk][4*g]);
          pm1 = fmaxf(pm1, sc[blk][4*g+1]);
          pm2 = fmaxf(pm2, sc[blk][4*g+2]);
          pm3 = fmaxf(pm3, sc[blk][4*g+3]);
        }
      float mx = fmaxf(fmaxf(pm0, pm1), fmaxf(pm2, pm3));
      mx = fmaxf(mx, __shfl_xor(mx, 32));
      // defer-max: rescale only when max grew past THR=8 (P bounded by 2^8)
      if (!__all(mx <= mst + 8.0f)) {
        float mnew = fmaxf(mst, mx);
        float fac = exp2f(mst - mnew);
        lst *= fac;
#pragma unroll
        for (int db = 0; db < 2; db++)
#pragma unroll
          for (int r2 = 0; r2 < 16; r2++) oaccT[db][r2] *= fac;
        mst = mnew;
      }
      float ps0 = 0.f, ps1 = 0.f, ps2 = 0.f, ps3 = 0.f;
#pragma unroll
      for (int blk = 0; blk < 2; blk++)
#pragma unroll
        for (int g = 0; g < 4; g++) {
          float p0 = exp2f(sc[blk][4*g]   - mst);
          float p1 = exp2f(sc[blk][4*g+1] - mst);
          float p2 = exp2f(sc[blk][4*g+2] - mst);
          float p3 = exp2f(sc[blk][4*g+3] - mst);
          ps0 += p0; ps1 += p1; ps2 += p2; ps3 += p3;
          uint2 val;
          val.x = cvt_pk_bf16(p0, p1);
          val.y = cvt_pk_bf16(p2, p3);
          int cbyte = (blk*64 + g*16 + hi*8) ^ swq;
          *reinterpret_cast<uint2*>(&Pw[(ql*128 + cbyte) >> 1]) = val;
        }
      float rs = (ps0 + ps1) + (ps2 + ps3);
      rs += __shfl_xor(rs, 32);
      lst += rs;
      // PV: O^T += mfma(A=V^T, B=P^T)
      __builtin_amdgcn_s_setprio(1);
#pragma unroll
      for (int ks = 0; ks < 4; ks++) {
        int cb = ks*32 + hi*16;
        short8 pa = *reinterpret_cast<const short8*>(&Pw[(ql*128 + (cb ^ swq)) >> 1]);
#pragma unroll
        for (int db = 0; db < 2; db++) {
          int row = db*32 + ql;
          int sw = (row & 7) << 4;
          short8 vf = *reinterpret_cast<const short8*>(&VT[cur][(row*128 + (cb ^ sw)) >> 1]);
          oaccT[db] = __builtin_amdgcn_mfma_f32_32x32x16_bf16(vf, pa, oaccT[db], 0, 0, 0);
        }
      }
      __builtin_amdgcn_s_setprio(0);
    }

    if (kt + 1 < nt) WRITE((kt + 1) & 1);
    __syncthreads();
  }

  // epilogue: lane owns q-column
  float inv = 1.0f / lst;
  unsigned short* ob = o + ((size_t)(bb * S_ + myq)) * D_ + hh * DH_;
#pragma unroll
  for (int db = 0; db < 2; db++)
#pragma unroll
    for (int g = 0; g < 8; g++) {
      int r2 = 2 * g;
      int dh = db*32 + (r2 & 3) + 8*(r2 >> 2) + 4*hi;
      unsigned pk = cvt_pk_bf16(oaccT[db][r2] * inv, oaccT[db][r2+1] * inv);
      *reinterpret_cast<unsigned*>(ob + dh) = pk;
    }
}

extern "C" void kernel_launch(void* const* d_in, const int* in_sizes, int n_in,
                              void* d_out, int out_size, void* d_ws, size_t ws_size,
                              hipStream_t stream) {
  (void)in_sizes; (void)n_in; (void)out_size; (void)ws_size;
  const float* x    = (const float*)d_in[0];
  const float* ln1g = (const float*)d_in[1];
  const float* ln1b = (const float*)d_in[2];
  const float* Wq   = (const float*)d_in[3];
  const float* bq   = (const float*)d_in[4];
  const float* Wk   = (const float*)d_in[5];
  const float* bk   = (const float*)d_in[6];
  const float* Wv   = (const float*)d_in[7];
  const float* bv   = (const float*)d_in[8];
  const float* Wo   = (const float*)d_in[9];
  const float* bo   = (const float*)d_in[10];
  const float* ln2g = (const float*)d_in[11];
  const float* ln2b = (const float*)d_in[12];
  const float* W1   = (const float*)d_in[13];
  const float* b1   = (const float*)d_in[14];
  const float* W2   = (const float*)d_in[15];
  const float* b2   = (const float*)d_in[16];
  float* out = (float*)d_out;

  char* ws = (char*)d_ws;
  size_t off = 0;
  auto alloc = [&](size_t bytes) {
    char* p = ws + off;
    off += (bytes + 255) & ~(size_t)255;
    return p;
  };
  // WqT/WkT/WvT contiguous => one [2304][768] B-matrix for fused QKV.
  unsigned short* WqT = (unsigned short*)alloc((size_t)D_*D_*2);
  unsigned short* WkT = (unsigned short*)alloc((size_t)D_*D_*2);
  unsigned short* WvT = (unsigned short*)alloc((size_t)D_*D_*2);
  unsigned short* WoT = (unsigned short*)alloc((size_t)D_*D_*2);
  unsigned short* W1T = (unsigned short*)alloc((size_t)D_*FF_*2);
  unsigned short* W2T = (unsigned short*)alloc((size_t)FF_*D_*2);
  unsigned short* h   = (unsigned short*)alloc((size_t)B_*S_*D_*2);
  unsigned short* qkv = (unsigned short*)alloc((size_t)B_*S_*LDQ*2);  // [8192][2304]
  unsigned short* ob  = (unsigned short*)alloc((size_t)B_*S_*D_*2);   // [8192][768]
  float* bias_cat     = (float*)alloc((size_t)3*D_*4);
  unsigned short* ffb = qkv;  // reuse qkv+ob region (50.3MB >= B*S*FF*2)
  unsigned short* h2  = h;    // reuse h

  const float qscale = 0.125f * 1.4426950408889634f;  // 1/sqrt(DH) * log2(e)

  dim3 tb(32, 8);
  transpose_cast_multi_kernel<<<6912, tb, 0, stream>>>(
      Wq, Wk, Wv, Wo, W1, W2, WqT, WkT, WvT, WoT, W1T, W2T);
  bias_cat_kernel<<<9, 256, 0, stream>>>(bq, bk, bv, bias_cat);

  layernorm_kernel<<<(B_*S_)/4, 256, 0, stream>>>(x, ln1g, ln1b, h);

  // fused QKV: one GEMM, N = 2304 (nN = 18), linear output [8192][2304]
  gemm_kernel<EPI_QKV><<<dim3(64*18), 256, 0, stream>>>(
      h, D_, WqT, D_, bias_cat, nullptr, nullptr, qkv, LDQ, qscale, 18);

  attn_kernel<<<dim3(768), 256, 0, stream>>>(qkv, ob);

  gemm_kernel<EPI_OPROJ><<<dim3(64*6), 256, 0, stream>>>(
      ob, D_, WoT, D_, bo, x, out, nullptr, D_, 1.0f, 6);

  layernorm_kernel<<<(B_*S_)/4, 256, 0, stream>>>(out, ln2g, ln2b, h2);

  gemm_kernel<EPI_GELU><<<dim3(64*24), 256, 0, stream>>>(
      h2, D_, W1T, D_, b1, nullptr, nullptr, ffb, FF_, 1.0f, 24);

  gemm_kernel<EPI_FINAL><<<dim3(64*6), 256, 0, stream>>>(
      ffb, FF_, W2T, FF_, b2, out, out, nullptr, D_, 1.0f, 6);
}